// Round 1
// baseline (793.084 us; speedup 1.0000x reference)
//
#include <hip/hip_runtime.h>
#include <math.h>

// ---------------- problem constants ----------------
constexpr int NN   = 50000;          // nodes
constexpr int NE   = 150000;         // edges
constexpr int DIN  = 48;
constexpr int DH   = 64;
constexpr int DE   = 16;
constexpr int NHD  = 10;             // heads
constexpr int NL   = 3;              // layers
constexpr int DOUTC= 128;
constexpr int NG   = 4096;           // graphs
constexpr int E2   = NE + NN;        // edges incl self loops
constexpr int SCAN_B  = 256;
constexpr int SCAN_NB = (NN + SCAN_B - 1) / SCAN_B;   // 196

// ---------------- preprocessing kernels ----------------
__global__ void k_loop_acc(const int* __restrict__ dst, const float* __restrict__ ea,
                           float* __restrict__ loop, int* __restrict__ cnt) {
    int tid = blockIdx.x * blockDim.x + threadIdx.x;
    if (tid >= NE * DE) return;
    int e = tid >> 4, d = tid & 15;
    int dn = dst[e];
    atomicAdd(&loop[dn * DE + d], ea[tid]);
    if (d == 0) atomicAdd(&cnt[dn], 1);
}

__global__ void k_loop_div(float* __restrict__ loop, const int* __restrict__ cnt) {
    int tid = blockIdx.x * blockDim.x + threadIdx.x;
    if (tid >= NN * DE) return;
    int c = cnt[tid >> 4];
    loop[tid] *= (c > 1) ? (1.0f / (float)c) : 1.0f;
}

__global__ void k_scan_a(const int* __restrict__ cnt, int* __restrict__ bsum) {
    __shared__ int s[SCAN_B];
    int i = blockIdx.x * SCAN_B + threadIdx.x;
    s[threadIdx.x] = (i < NN) ? (cnt[i] + 1) : 0;   // +1 = self loop
    __syncthreads();
    for (int off = SCAN_B / 2; off > 0; off >>= 1) {
        if (threadIdx.x < off) s[threadIdx.x] += s[threadIdx.x + off];
        __syncthreads();
    }
    if (threadIdx.x == 0) bsum[blockIdx.x] = s[0];
}

__global__ void k_scan_b(int* __restrict__ bsum) {
    if (threadIdx.x == 0 && blockIdx.x == 0) {
        int acc = 0;
        for (int i = 0; i < SCAN_NB; ++i) { int v = bsum[i]; bsum[i] = acc; acc += v; }
    }
}

__global__ void k_scan_c(const int* __restrict__ cnt, const int* __restrict__ bsum,
                         int* __restrict__ rp) {
    __shared__ int s[SCAN_B];
    int i = blockIdx.x * SCAN_B + threadIdx.x;
    int v = (i < NN) ? (cnt[i] + 1) : 0;
    s[threadIdx.x] = v;
    __syncthreads();
    for (int off = 1; off < SCAN_B; off <<= 1) {
        int t = (threadIdx.x >= off) ? s[threadIdx.x - off] : 0;
        __syncthreads();
        s[threadIdx.x] += t;
        __syncthreads();
    }
    if (i < NN) {
        int excl = bsum[blockIdx.x] + s[threadIdx.x] - v;
        rp[i] = excl;
        if (i == NN - 1) rp[NN] = excl + v;
    }
}

__global__ void k_csr_fill(const int* __restrict__ dst, const int* __restrict__ rp,
                           int* __restrict__ cursor, int* __restrict__ eidx) {
    int e = blockIdx.x * blockDim.x + threadIdx.x;
    if (e >= E2) return;
    int d = (e < NE) ? dst[e] : (e - NE);
    int pos = atomicAdd(&cursor[d], 1);
    eidx[rp[d] + pos] = e;
}

// ---------------- embedding GEMM: h = x @ W_emb + b ----------------
__global__ void k_emb(const float* __restrict__ x, const float* __restrict__ W,
                      const float* __restrict__ b, float* __restrict__ h) {
    __shared__ float Wl[DIN * DH];                      // 12 KB
    for (int i = threadIdx.x; i < DIN * DH; i += blockDim.x) Wl[i] = W[i];
    __syncthreads();
    int n = blockIdx.x * (blockDim.x / DH) + threadIdx.x / DH;
    int c = threadIdx.x & (DH - 1);
    if (n >= NN) return;
    const float* xr = x + (size_t)n * DIN;
    float acc = b[c];
#pragma unroll
    for (int k = 0; k < DIN; ++k) acc += xr[k] * Wl[k * DH + c];
    h[(size_t)n * DH + c] = acc;
}

// ---------------- per-layer combined attention weights ----------------
// Wcomb[k][j] (64x20): j<10 -> sum_f Ws[k, j*64+f]*att_src[j,f]; j>=10 -> att_dst
// We[d][h]   (16x10): sum_f W_edge[d, h*64+f]*att_edge[h,f]
__global__ void k_comb(const float* __restrict__ Ws, const float* __restrict__ asrc,
                       const float* __restrict__ adst, const float* __restrict__ We_in,
                       const float* __restrict__ aedge, float* __restrict__ Wcomb,
                       float* __restrict__ We, int layer) {
    int tid = blockIdx.x * blockDim.x + threadIdx.x;
    if (tid < DH * 2 * NHD) {                      // 1280
        int k = tid / 20, j = tid % 20;
        int hh = j % NHD;
        const float* a = ((j < NHD) ? asrc : adst) + (size_t)layer * NHD * DH + hh * DH;
        const float* w = Ws + ((size_t)layer * DH + k) * (NHD * DH) + hh * DH;
        float s = 0.f;
#pragma unroll
        for (int f = 0; f < DH; ++f) s += w[f] * a[f];
        Wcomb[tid] = s;
    } else if (tid < DH * 2 * NHD + DE * NHD) {    // +160
        int t = tid - DH * 2 * NHD;
        int d = t / NHD, hh = t % NHD;
        const float* a = aedge + (size_t)layer * NHD * DH + hh * DH;
        const float* w = We_in + ((size_t)layer * DE + d) * (NHD * DH) + hh * DH;
        float s = 0.f;
#pragma unroll
        for (int f = 0; f < DH; ++f) s += w[f] * a[f];
        We[t] = s;
    }
}

// ---------------- S[n][0..9]=a_s, S[n][10..19]=a_d ----------------
__global__ void k_scores(const float* __restrict__ h, const float* __restrict__ Wcomb,
                         float* __restrict__ S) {
    __shared__ float wl[DH * 20];
    for (int i = threadIdx.x; i < DH * 20; i += blockDim.x) wl[i] = Wcomb[i];
    __syncthreads();
    int tid = blockIdx.x * blockDim.x + threadIdx.x;
    if (tid >= NN * 20) return;
    int n = tid / 20, j = tid % 20;
    const float* hr = h + (size_t)n * DH;
    float s = 0.f;
#pragma unroll 16
    for (int k = 0; k < DH; ++k) s += hr[k] * wl[k * 20 + j];
    S[tid] = s;
}

// ---------------- a_e[e][h] for all E2 edges ----------------
__global__ void k_ae(const float* __restrict__ ea, const float* __restrict__ loop,
                     const float* __restrict__ We, float* __restrict__ a_e) {
    __shared__ float wl[DE * NHD];
    if (threadIdx.x < DE * NHD) wl[threadIdx.x] = We[threadIdx.x];
    __syncthreads();
    int tid = blockIdx.x * blockDim.x + threadIdx.x;
    if (tid >= E2 * NHD) return;
    int e = tid / NHD, hh = tid % NHD;
    const float* ar = (e < NE) ? (ea + (size_t)e * DE) : (loop + (size_t)(e - NE) * DE);
    float s = 0.f;
#pragma unroll
    for (int d = 0; d < DE; ++d) s += ar[d] * wl[d * NHD + hh];
    a_e[tid] = s;
}

// ---------------- per-node softmax + aggregation into G ----------------
// one wave per node; lanes 0..9 do online softmax per head, all 64 lanes accumulate G
constexpr int AGG_W = 4;     // waves per block
constexpr int CHUNK = 32;
__global__ void k_agg(const float* __restrict__ S, const float* __restrict__ a_e,
                      const float* __restrict__ h, const int* __restrict__ rp,
                      const int* __restrict__ eidx, const int* __restrict__ src,
                      float* __restrict__ G) {
    __shared__ float att[AGG_W][CHUNK][NHD];
    int w = threadIdx.x >> 6, lane = threadIdx.x & 63;
    int n = blockIdx.x * AGG_W + w;
    if (n >= NN) return;
    int r0 = rp[n], deg = rp[n + 1] - r0;
    float m = -1e30f, z = 0.f, ad = 0.f;
    if (lane < NHD) {
        ad = S[(size_t)n * 20 + 10 + lane];
        for (int e = 0; e < deg; ++e) {
            int eid = eidx[r0 + e];
            int sn = (eid < NE) ? src[eid] : n;
            float a = S[(size_t)sn * 20 + lane] + ad + a_e[(size_t)eid * NHD + lane];
            a = (a > 0.f) ? a : 0.2f * a;
            float mn = fmaxf(m, a);
            z = z * __expf(m - mn) + __expf(a - mn);
            m = mn;
        }
    }
    float g[NHD];
#pragma unroll
    for (int i = 0; i < NHD; ++i) g[i] = 0.f;
    for (int c0 = 0; c0 < deg; c0 += CHUNK) {
        int ce = deg - c0; if (ce > CHUNK) ce = CHUNK;
        if (lane < NHD) {
            for (int e = 0; e < ce; ++e) {
                int eid = eidx[r0 + c0 + e];
                int sn = (eid < NE) ? src[eid] : n;
                float a = S[(size_t)sn * 20 + lane] + ad + a_e[(size_t)eid * NHD + lane];
                a = (a > 0.f) ? a : 0.2f * a;
                att[w][e][lane] = __expf(a - m) / z;
            }
        }
        __builtin_amdgcn_wave_barrier();    // same-wave LDS ordering
        for (int e = 0; e < ce; ++e) {
            int eid = eidx[r0 + c0 + e];
            int sn = (eid < NE) ? src[eid] : n;
            float hv = h[(size_t)sn * DH + lane];
#pragma unroll
            for (int i = 0; i < NHD; ++i) g[i] += att[w][e][i] * hv;
        }
        __builtin_amdgcn_wave_barrier();
    }
#pragma unroll
    for (int i = 0; i < NHD; ++i) G[(size_t)n * 640 + i * 64 + lane] = g[i];
}

// ---------------- xc = G @ B + epilogue; h += gelu(bn(xc + bias)) ----------------
// B[j][f] = Ws[layer][ j&63 ][ (j>>6)*64 + f ] * 0.1  (head mean folded in)
__global__ __launch_bounds__(256) void k_gemm_xc(
        const float* __restrict__ G, const float* __restrict__ Ws,
        const float* __restrict__ bias, const float* __restrict__ gam,
        const float* __restrict__ bet, const float* __restrict__ mean,
        const float* __restrict__ var, float* __restrict__ h, int layer) {
    __shared__ float As[64][33];
    __shared__ float Bs[32][64];
    int tid = threadIdx.x;
    int tx = tid & 15, ty = tid >> 4;
    int row0 = blockIdx.x * 64;
    float c[4][4];
#pragma unroll
    for (int i = 0; i < 4; ++i)
#pragma unroll
        for (int j = 0; j < 4; ++j) c[i][j] = 0.f;

    int am = tid >> 2, ak = (tid & 3) * 8;   // A: 64 rows x 32 k
    int bk = tid >> 3, bc = (tid & 7) * 8;   // B: 32 k x 64 cols
    const float* wsl = Ws + (size_t)layer * DH * 640;

    for (int k0 = 0; k0 < 640; k0 += 32) {
        int node = row0 + am;
        if (node < NN) {
            const float* gp = G + (size_t)node * 640 + k0 + ak;
            float4 v0 = *(const float4*)gp;
            float4 v1 = *(const float4*)(gp + 4);
            As[am][ak+0]=v0.x; As[am][ak+1]=v0.y; As[am][ak+2]=v0.z; As[am][ak+3]=v0.w;
            As[am][ak+4]=v1.x; As[am][ak+5]=v1.y; As[am][ak+6]=v1.z; As[am][ak+7]=v1.w;
        } else {
#pragma unroll
            for (int q = 0; q < 8; ++q) As[am][ak+q] = 0.f;
        }
        {
            int j = k0 + bk;
            int hh = j >> 6, kk = j & 63;
            const float* bp = wsl + (size_t)kk * 640 + hh * 64 + bc;
            float4 v0 = *(const float4*)bp;
            float4 v1 = *(const float4*)(bp + 4);
            Bs[bk][bc+0]=v0.x*0.1f; Bs[bk][bc+1]=v0.y*0.1f; Bs[bk][bc+2]=v0.z*0.1f; Bs[bk][bc+3]=v0.w*0.1f;
            Bs[bk][bc+4]=v1.x*0.1f; Bs[bk][bc+5]=v1.y*0.1f; Bs[bk][bc+6]=v1.z*0.1f; Bs[bk][bc+7]=v1.w*0.1f;
        }
        __syncthreads();
#pragma unroll
        for (int k = 0; k < 32; ++k) {
            float a0 = As[ty*4+0][k], a1 = As[ty*4+1][k], a2 = As[ty*4+2][k], a3 = As[ty*4+3][k];
            float b0 = Bs[k][tx*4+0], b1 = Bs[k][tx*4+1], b2 = Bs[k][tx*4+2], b3 = Bs[k][tx*4+3];
            c[0][0]+=a0*b0; c[0][1]+=a0*b1; c[0][2]+=a0*b2; c[0][3]+=a0*b3;
            c[1][0]+=a1*b0; c[1][1]+=a1*b1; c[1][2]+=a1*b2; c[1][3]+=a1*b3;
            c[2][0]+=a2*b0; c[2][1]+=a2*b1; c[2][2]+=a2*b2; c[2][3]+=a2*b3;
            c[3][0]+=a3*b0; c[3][1]+=a3*b1; c[3][2]+=a3*b2; c[3][3]+=a3*b3;
        }
        __syncthreads();
    }
#pragma unroll
    for (int i = 0; i < 4; ++i) {
        int node = row0 + ty * 4 + i;
        if (node >= NN) continue;
#pragma unroll
        for (int j = 0; j < 4; ++j) {
            int col = tx * 4 + j;
            float v = c[i][j] + bias[col];
            v = (v - mean[col]) * gam[col] * rsqrtf(var[col] + 1e-5f) + bet[col];
            v = 0.5f * v * (1.0f + erff(v * 0.70710678118654752f));   // exact gelu
            h[(size_t)node * DH + col] += v;
        }
    }
}

// ---------------- readout ----------------
__global__ void k_gcnt(const int* __restrict__ batch, int* __restrict__ gcnt) {
    int n = blockIdx.x * blockDim.x + threadIdx.x;
    if (n < NN) atomicAdd(&gcnt[batch[n]], 1);
}

constexpr int OUT_NODES = 32;
__global__ void k_out(const float* __restrict__ h, const float* __restrict__ W,
                      const float* __restrict__ b, const int* __restrict__ batch,
                      float* __restrict__ gsum) {
    __shared__ float Wl[DH * DOUTC];          // 32 KB
    __shared__ float hl[OUT_NODES][DH];       // 8 KB
    __shared__ int   bl[OUT_NODES];
    int n0 = blockIdx.x * OUT_NODES;
    for (int i = threadIdx.x; i < DH * DOUTC; i += 128) Wl[i] = W[i];
    for (int i = threadIdx.x; i < OUT_NODES * DH; i += 128) {
        int nn = n0 + (i >> 6);
        hl[i >> 6][i & 63] = (nn < NN) ? h[(size_t)nn * DH + (i & 63)] : 0.f;
    }
    if (threadIdx.x < OUT_NODES) {
        int nn = n0 + threadIdx.x;
        bl[threadIdx.x] = (nn < NN) ? batch[nn] : -1;
    }
    __syncthreads();
    int col = threadIdx.x;
    float acc = 0.f; int cur = -1;
    for (int t = 0; t < OUT_NODES; ++t) {
        if (n0 + t >= NN) break;
        float s = b[col];
#pragma unroll 16
        for (int k = 0; k < DH; ++k) s += hl[t][k] * Wl[k * DOUTC + col];
        int bg = bl[t];
        if (bg != cur) {
            if (cur >= 0) atomicAdd(&gsum[(size_t)cur * DOUTC + col], acc);
            cur = bg; acc = s;
        } else acc += s;
    }
    if (cur >= 0) atomicAdd(&gsum[(size_t)cur * DOUTC + col], acc);
}

__global__ void k_fin(const float* __restrict__ gsum, const int* __restrict__ gcnt,
                      float* __restrict__ out) {
    int tid = blockIdx.x * blockDim.x + threadIdx.x;
    if (tid >= NG * DOUTC) return;
    int g = tid >> 7;
    int c = gcnt[g];
    out[tid] = gsum[tid] * ((c > 1) ? (1.0f / (float)c) : 1.0f);
}

// ---------------- launcher ----------------
extern "C" void kernel_launch(void* const* d_in, const int* in_sizes, int n_in,
                              void* d_out, int out_size, void* d_ws, size_t ws_size,
                              hipStream_t stream) {
    const float* x        = (const float*)d_in[0];
    const float* edge_attr= (const float*)d_in[1];
    const float* W_emb    = (const float*)d_in[2];
    const float* b_emb    = (const float*)d_in[3];
    const float* Ws       = (const float*)d_in[4];
    const float* att_src  = (const float*)d_in[5];
    const float* att_dst  = (const float*)d_in[6];
    const float* att_edge = (const float*)d_in[7];
    const float* W_edge   = (const float*)d_in[8];
    const float* bias     = (const float*)d_in[9];
    const float* bn_gamma = (const float*)d_in[10];
    const float* bn_beta  = (const float*)d_in[11];
    const float* bn_mean  = (const float*)d_in[12];
    const float* bn_var   = (const float*)d_in[13];
    const float* W_out    = (const float*)d_in[14];
    const float* b_out    = (const float*)d_in[15];
    const int*   srcp     = (const int*)d_in[16];
    const int*   dstp     = srcp + NE;
    const int*   batch    = (const int*)d_in[17];
    float* out = (float*)d_out;

    char* wsb = (char*)d_ws;
    size_t off = 0;
    auto alloc = [&](size_t bytes) -> void* {
        void* p = (void*)(wsb + off);
        off += (bytes + 255) & ~(size_t)255;
        return p;
    };
    float* h     = (float*)alloc((size_t)NN * DH * 4);
    float* S     = (float*)alloc((size_t)NN * 20 * 4);
    float* a_e   = (float*)alloc((size_t)E2 * NHD * 4);
    float* G     = (float*)alloc((size_t)NN * 640 * 4);
    float* loop  = (float*)alloc((size_t)NN * DE * 4);
    int*   cnt   = (int*)alloc((size_t)NN * 4);
    int*   rp    = (int*)alloc((size_t)(NN + 1) * 4);
    int*   cursor= (int*)alloc((size_t)NN * 4);
    int*   eidx  = (int*)alloc((size_t)E2 * 4);
    int*   bsum  = (int*)alloc((size_t)SCAN_NB * 4);
    float* Wcomb = (float*)alloc((size_t)DH * 20 * 4);
    float* We    = (float*)alloc((size_t)DE * NHD * 4);
    float* gsum  = (float*)alloc((size_t)NG * DOUTC * 4);
    int*   gcnt  = (int*)alloc((size_t)NG * 4);

    hipMemsetAsync(loop,   0, (size_t)NN * DE * 4, stream);
    hipMemsetAsync(cnt,    0, (size_t)NN * 4, stream);
    hipMemsetAsync(cursor, 0, (size_t)NN * 4, stream);
    hipMemsetAsync(gsum,   0, (size_t)NG * DOUTC * 4, stream);
    hipMemsetAsync(gcnt,   0, (size_t)NG * 4, stream);

    // preprocessing: self-loop attrs + dst-CSR
    k_loop_acc<<<(NE * DE + 255) / 256, 256, 0, stream>>>(dstp, edge_attr, loop, cnt);
    k_loop_div<<<(NN * DE + 255) / 256, 256, 0, stream>>>(loop, cnt);
    k_scan_a<<<SCAN_NB, SCAN_B, 0, stream>>>(cnt, bsum);
    k_scan_b<<<1, 64, 0, stream>>>(bsum);
    k_scan_c<<<SCAN_NB, SCAN_B, 0, stream>>>(cnt, bsum, rp);
    k_csr_fill<<<(E2 + 255) / 256, 256, 0, stream>>>(dstp, rp, cursor, eidx);

    // embedding
    k_emb<<<(NN + 3) / 4, 256, 0, stream>>>(x, W_emb, b_emb, h);

    for (int l = 0; l < NL; ++l) {
        k_comb<<<6, 256, 0, stream>>>(Ws, att_src, att_dst, W_edge, att_edge, Wcomb, We, l);
        k_scores<<<(NN * 20 + 255) / 256, 256, 0, stream>>>(h, Wcomb, S);
        k_ae<<<(E2 * NHD + 255) / 256, 256, 0, stream>>>(edge_attr, loop, We, a_e);
        k_agg<<<(NN + AGG_W - 1) / AGG_W, AGG_W * 64, 0, stream>>>(S, a_e, h, rp, eidx, srcp, G);
        k_gemm_xc<<<(NN + 63) / 64, 256, 0, stream>>>(G, Ws, bias + l * DH, bn_gamma + l * DH,
                                                      bn_beta + l * DH, bn_mean + l * DH,
                                                      bn_var + l * DH, h, l);
    }

    // readout
    k_gcnt<<<(NN + 255) / 256, 256, 0, stream>>>(batch, gcnt);
    k_out<<<(NN + OUT_NODES - 1) / OUT_NODES, 128, 0, stream>>>(h, W_out, b_out, batch, gsum);
    k_fin<<<(NG * DOUTC + 255) / 256, 256, 0, stream>>>(gsum, gcnt, out);
}

// Round 2
// 645.053 us; speedup vs baseline: 1.2295x; 1.2295x over previous
//
#include <hip/hip_runtime.h>
#include <math.h>

// ---------------- problem constants ----------------
constexpr int NN   = 50000;          // nodes
constexpr int NE   = 150000;         // edges
constexpr int DIN  = 48;
constexpr int DH   = 64;
constexpr int DE   = 16;
constexpr int NHD  = 10;             // heads
constexpr int NL   = 3;              // layers
constexpr int DOUTC= 128;
constexpr int NG   = 4096;           // graphs
constexpr int E2   = NE + NN;        // edges incl self loops
constexpr int SCAN_B  = 256;
constexpr int SCAN_NB = (NN + SCAN_B - 1) / SCAN_B;   // 196

typedef __bf16 v8bf __attribute__((ext_vector_type(8)));
typedef short  v8s  __attribute__((ext_vector_type(8)));
typedef float  v4f  __attribute__((ext_vector_type(4)));

__device__ inline unsigned short f2bf(float f) {
    unsigned u = __builtin_bit_cast(unsigned, f);
    unsigned r = (u + 0x7FFFu + ((u >> 16) & 1u)) >> 16;
    return (unsigned short)r;
}

// ---------------- preprocessing kernels ----------------
__global__ void k_loop_acc(const int* __restrict__ dst, const float* __restrict__ ea,
                           float* __restrict__ loop, int* __restrict__ cnt) {
    int tid = blockIdx.x * blockDim.x + threadIdx.x;
    if (tid >= NE * DE) return;
    int e = tid >> 4, d = tid & 15;
    int dn = dst[e];
    atomicAdd(&loop[dn * DE + d], ea[tid]);
    if (d == 0) atomicAdd(&cnt[dn], 1);
}

__global__ void k_loop_div(float* __restrict__ loop, const int* __restrict__ cnt) {
    int tid = blockIdx.x * blockDim.x + threadIdx.x;
    if (tid >= NN * DE) return;
    int c = cnt[tid >> 4];
    loop[tid] *= (c > 1) ? (1.0f / (float)c) : 1.0f;
}

__global__ void k_scan_a(const int* __restrict__ cnt, int* __restrict__ bsum) {
    __shared__ int s[SCAN_B];
    int i = blockIdx.x * SCAN_B + threadIdx.x;
    s[threadIdx.x] = (i < NN) ? (cnt[i] + 1) : 0;   // +1 = self loop
    __syncthreads();
    for (int off = SCAN_B / 2; off > 0; off >>= 1) {
        if (threadIdx.x < off) s[threadIdx.x] += s[threadIdx.x + off];
        __syncthreads();
    }
    if (threadIdx.x == 0) bsum[blockIdx.x] = s[0];
}

__global__ void k_scan_b(int* __restrict__ bsum) {
    if (threadIdx.x == 0 && blockIdx.x == 0) {
        int acc = 0;
        for (int i = 0; i < SCAN_NB; ++i) { int v = bsum[i]; bsum[i] = acc; acc += v; }
    }
}

__global__ void k_scan_c(const int* __restrict__ cnt, const int* __restrict__ bsum,
                         int* __restrict__ rp) {
    __shared__ int s[SCAN_B];
    int i = blockIdx.x * SCAN_B + threadIdx.x;
    int v = (i < NN) ? (cnt[i] + 1) : 0;
    s[threadIdx.x] = v;
    __syncthreads();
    for (int off = 1; off < SCAN_B; off <<= 1) {
        int t = (threadIdx.x >= off) ? s[threadIdx.x - off] : 0;
        __syncthreads();
        s[threadIdx.x] += t;
        __syncthreads();
    }
    if (i < NN) {
        int excl = bsum[blockIdx.x] + s[threadIdx.x] - v;
        rp[i] = excl;
        if (i == NN - 1) rp[NN] = excl + v;
    }
}

__global__ void k_csr_fill(const int* __restrict__ dst, const int* __restrict__ rp,
                           int* __restrict__ cursor, int* __restrict__ eidx) {
    int e = blockIdx.x * blockDim.x + threadIdx.x;
    if (e >= E2) return;
    int d = (e < NE) ? dst[e] : (e - NE);
    int pos = atomicAdd(&cursor[d], 1);
    eidx[rp[d] + pos] = e;
}

// ---------------- embedding GEMM: h = x @ W_emb + b ----------------
__global__ void k_emb(const float* __restrict__ x, const float* __restrict__ W,
                      const float* __restrict__ b, float* __restrict__ h) {
    __shared__ float Wl[DIN * DH];                      // 12 KB
    for (int i = threadIdx.x; i < DIN * DH; i += blockDim.x) Wl[i] = W[i];
    __syncthreads();
    int n = blockIdx.x * (blockDim.x / DH) + threadIdx.x / DH;
    int c = threadIdx.x & (DH - 1);
    if (n >= NN) return;
    const float* xr = x + (size_t)n * DIN;
    float acc = b[c];
#pragma unroll
    for (int k = 0; k < DIN; ++k) acc += xr[k] * Wl[k * DH + c];
    h[(size_t)n * DH + c] = acc;
}

// ---------------- per-layer combined attention weights ----------------
__global__ void k_comb(const float* __restrict__ Ws, const float* __restrict__ asrc,
                       const float* __restrict__ adst, const float* __restrict__ We_in,
                       const float* __restrict__ aedge, float* __restrict__ Wcomb,
                       float* __restrict__ We, int layer) {
    int tid = blockIdx.x * blockDim.x + threadIdx.x;
    if (tid < DH * 2 * NHD) {                      // 1280
        int k = tid / 20, j = tid % 20;
        int hh = j % NHD;
        const float* a = ((j < NHD) ? asrc : adst) + (size_t)layer * NHD * DH + hh * DH;
        const float* w = Ws + ((size_t)layer * DH + k) * (NHD * DH) + hh * DH;
        float s = 0.f;
#pragma unroll
        for (int f = 0; f < DH; ++f) s += w[f] * a[f];
        Wcomb[tid] = s;
    } else if (tid < DH * 2 * NHD + DE * NHD) {    // +160
        int t = tid - DH * 2 * NHD;
        int d = t / NHD, hh = t % NHD;
        const float* a = aedge + (size_t)layer * NHD * DH + hh * DH;
        const float* w = We_in + ((size_t)layer * DE + d) * (NHD * DH) + hh * DH;
        float s = 0.f;
#pragma unroll
        for (int f = 0; f < DH; ++f) s += w[f] * a[f];
        We[t] = s;
    }
}

// ---------------- Bt[f][j] = Ws[layer][j&63][(j>>6)*64 + f] * 0.1, bf16 ----------------
__global__ void k_prepB(const float* __restrict__ Ws, unsigned short* __restrict__ Bt,
                        int layer) {
    int tid = blockIdx.x * blockDim.x + threadIdx.x;
    if (tid >= DH * 640) return;
    int f = tid / 640, j = tid % 640;
    int hh = j >> 6, k = j & 63;
    float v = Ws[(size_t)layer * DH * 640 + (size_t)k * 640 + hh * 64 + f] * 0.1f;
    Bt[tid] = f2bf(v);
}

// ---------------- S[n][0..9]=a_s, S[n][10..19]=a_d ----------------
__global__ void k_scores(const float* __restrict__ h, const float* __restrict__ Wcomb,
                         float* __restrict__ S) {
    __shared__ float wl[DH * 20];
    for (int i = threadIdx.x; i < DH * 20; i += blockDim.x) wl[i] = Wcomb[i];
    __syncthreads();
    int tid = blockIdx.x * blockDim.x + threadIdx.x;
    if (tid >= NN * 20) return;
    int n = tid / 20, j = tid % 20;
    const float* hr = h + (size_t)n * DH;
    float s = 0.f;
#pragma unroll 16
    for (int k = 0; k < DH; ++k) s += hr[k] * wl[k * 20 + j];
    S[tid] = s;
}

// ---------------- a_e[e][h] for all E2 edges ----------------
__global__ void k_ae(const float* __restrict__ ea, const float* __restrict__ loop,
                     const float* __restrict__ We, float* __restrict__ a_e) {
    __shared__ float wl[DE * NHD];
    if (threadIdx.x < DE * NHD) wl[threadIdx.x] = We[threadIdx.x];
    __syncthreads();
    int tid = blockIdx.x * blockDim.x + threadIdx.x;
    if (tid >= E2 * NHD) return;
    int e = tid / NHD, hh = tid % NHD;
    const float* ar = (e < NE) ? (ea + (size_t)e * DE) : (loop + (size_t)(e - NE) * DE);
    float s = 0.f;
#pragma unroll
    for (int d = 0; d < DE; ++d) s += ar[d] * wl[d * NHD + hh];
    a_e[tid] = s;
}

// ---------------- fused layer: softmax-agg (LDS G tile) + MFMA GEMM + epilogue ----------------
// block = 256 threads = 4 waves, 32 nodes/block; wave w owns local nodes w*8..w*8+7.
// Phase A: flash-style online softmax + aggregation, g -> bf16 G tile in LDS.
// Phase B: xc[32x64] = G @ B via mfma_f32_16x16x32_bf16, B-frags from global Bt (L2-hot).
constexpr int CE = 6;   // edges per chunk (60 lanes = 6 edges x 10 heads)
__global__ __launch_bounds__(256) void k_layer(
        const float* __restrict__ S, const float* __restrict__ a_e,
        const float* __restrict__ hin, const int* __restrict__ rp,
        const int* __restrict__ eidx, const int* __restrict__ src,
        const unsigned short* __restrict__ Bt,
        const float* __restrict__ bias, const float* __restrict__ gam,
        const float* __restrict__ bet, const float* __restrict__ mean,
        const float* __restrict__ var, float* __restrict__ hout) {
    __shared__ __align__(16) unsigned short Gl[32][648];  // 41.5 KB, +8 pad (4-bank skew)
    __shared__ float ach[4][CE][NHD];
    __shared__ float pch[4][CE][NHD];
    __shared__ int   snl[4][CE];
    __shared__ float scl[4][NHD];
    __shared__ float zbl[4][NHD];

    const int tid = threadIdx.x;
    const int w = tid >> 6, lane = tid & 63;
    const int blk = blockIdx.x;
    const int el = lane / NHD;        // edge slot within chunk (0..6)
    const int hh = lane % NHD;        // head

    // ---------------- Phase A ----------------
    for (int i = 0; i < 8; ++i) {
        const int local = w * 8 + i;
        const int n = blk * 32 + local;
        float g[NHD];
#pragma unroll
        for (int q = 0; q < NHD; ++q) g[q] = 0.f;
        float m = -1e30f, z = 0.f;

        if (n < NN) {
            const int r0 = rp[n], deg = rp[n + 1] - r0;
            for (int c0 = 0; c0 < deg; c0 += CE) {
                int ce = deg - c0; if (ce > CE) ce = CE;
                // step 1: alpha for (e,h) lanes
                if (el < ce && lane < CE * NHD) {
                    int eid = eidx[r0 + c0 + el];
                    int sn = (eid < NE) ? src[eid] : n;
                    float a = S[(size_t)sn * 20 + hh] + S[(size_t)n * 20 + 10 + hh]
                            + a_e[(size_t)eid * NHD + hh];
                    a = (a > 0.f) ? a : 0.2f * a;
                    ach[w][el][hh] = a;
                    if (hh == 0) snl[w][el] = sn;
                }
                __builtin_amdgcn_wave_barrier();
                // step 2: online max/z update (lanes 0..9)
                if (lane < NHD) {
                    float mc = -1e30f;
                    for (int e = 0; e < ce; ++e) mc = fmaxf(mc, ach[w][e][lane]);
                    float mn = fmaxf(m, mc);
                    float sc = __expf(m - mn);
                    float zc = 0.f;
                    for (int e = 0; e < ce; ++e) {
                        float p = __expf(ach[w][e][lane] - mn);
                        pch[w][e][lane] = p;
                        zc += p;
                    }
                    z = z * sc + zc;
                    m = mn;
                    scl[w][lane] = sc;
                }
                __builtin_amdgcn_wave_barrier();
                // step 3: rescale + accumulate (all 64 lanes; lane = feature k)
                {
#pragma unroll
                    for (int q = 0; q < NHD; ++q) g[q] *= scl[w][q];
                    for (int e = 0; e < ce; ++e) {
                        int sn2 = snl[w][e];
                        float hv = hin[(size_t)sn2 * DH + lane];
#pragma unroll
                        for (int q = 0; q < NHD; ++q) g[q] += pch[w][e][q] * hv;
                    }
                }
                __builtin_amdgcn_wave_barrier();
            }
            if (lane < NHD) zbl[w][lane] = z;
            __builtin_amdgcn_wave_barrier();
        }
        // write G row (zeros for invalid nodes)
#pragma unroll
        for (int q = 0; q < NHD; ++q) {
            float val = (n < NN) ? (g[q] / zbl[w][q]) : 0.f;
            Gl[local][q * 64 + lane] = f2bf(val);
        }
        __builtin_amdgcn_wave_barrier();
    }

    __syncthreads();

    // ---------------- Phase B: xc = G @ B, MFMA ----------------
    const int rt = w & 1;             // row tile (16 nodes)
    const int cb = (w >> 1) * 2;      // first of 2 col tiles
    const int la = lane & 15, lb = lane >> 4;
    v4f acc0 = {0.f, 0.f, 0.f, 0.f}, acc1 = {0.f, 0.f, 0.f, 0.f};

    const size_t b0row = (size_t)(cb * 16 + la) * 640;
    const size_t b1row = (size_t)(cb * 16 + 16 + la) * 640;
#pragma unroll 4
    for (int t = 0; t < 20; ++t) {
        const int koff = t * 32 + lb * 8;
        v8s av = *(const v8s*)&Gl[rt * 16 + la][koff];
        v8s b0 = *(const v8s*)&Bt[b0row + koff];
        v8s b1 = *(const v8s*)&Bt[b1row + koff];
        acc0 = __builtin_amdgcn_mfma_f32_16x16x32_bf16(
                   __builtin_bit_cast(v8bf, av), __builtin_bit_cast(v8bf, b0), acc0, 0, 0, 0);
        acc1 = __builtin_amdgcn_mfma_f32_16x16x32_bf16(
                   __builtin_bit_cast(v8bf, av), __builtin_bit_cast(v8bf, b1), acc1, 0, 0, 0);
    }

    // epilogue: bias + BN + gelu + residual
#pragma unroll
    for (int cc = 0; cc < 2; ++cc) {
        v4f a = cc ? acc1 : acc0;
        const int f = (cb + cc) * 16 + la;
        const float bi = bias[f], gm = gam[f], bt_ = bet[f], mu = mean[f];
        const float iv = rsqrtf(var[f] + 1e-5f);
#pragma unroll
        for (int r = 0; r < 4; ++r) {
            const int local = rt * 16 + lb * 4 + r;
            const int n = blk * 32 + local;
            if (n < NN) {
                float v = a[r] + bi;
                v = (v - mu) * gm * iv + bt_;
                v = 0.5f * v * (1.0f + erff(v * 0.70710678118654752f));
                hout[(size_t)n * DH + f] = hin[(size_t)n * DH + f] + v;
            }
        }
    }
}

// ---------------- readout ----------------
__global__ void k_gcnt(const int* __restrict__ batch, int* __restrict__ gcnt) {
    int n = blockIdx.x * blockDim.x + threadIdx.x;
    if (n < NN) atomicAdd(&gcnt[batch[n]], 1);
}

constexpr int OUT_NODES = 32;
__global__ void k_out(const float* __restrict__ h, const float* __restrict__ W,
                      const float* __restrict__ b, const int* __restrict__ batch,
                      float* __restrict__ gsum) {
    __shared__ float Wl[DH * DOUTC];          // 32 KB
    __shared__ float hl[OUT_NODES][DH];       // 8 KB
    __shared__ int   bl[OUT_NODES];
    int n0 = blockIdx.x * OUT_NODES;
    for (int i = threadIdx.x; i < DH * DOUTC; i += 128) Wl[i] = W[i];
    for (int i = threadIdx.x; i < OUT_NODES * DH; i += 128) {
        int nn = n0 + (i >> 6);
        hl[i >> 6][i & 63] = (nn < NN) ? h[(size_t)nn * DH + (i & 63)] : 0.f;
    }
    if (threadIdx.x < OUT_NODES) {
        int nn = n0 + threadIdx.x;
        bl[threadIdx.x] = (nn < NN) ? batch[nn] : -1;
    }
    __syncthreads();
    int col = threadIdx.x;
    float acc = 0.f; int cur = -1;
    for (int t = 0; t < OUT_NODES; ++t) {
        if (n0 + t >= NN) break;
        float s = b[col];
#pragma unroll 16
        for (int k = 0; k < DH; ++k) s += hl[t][k] * Wl[k * DOUTC + col];
        int bg = bl[t];
        if (bg != cur) {
            if (cur >= 0) atomicAdd(&gsum[(size_t)cur * DOUTC + col], acc);
            cur = bg; acc = s;
        } else acc += s;
    }
    if (cur >= 0) atomicAdd(&gsum[(size_t)cur * DOUTC + col], acc);
}

__global__ void k_fin(const float* __restrict__ gsum, const int* __restrict__ gcnt,
                      float* __restrict__ out) {
    int tid = blockIdx.x * blockDim.x + threadIdx.x;
    if (tid >= NG * DOUTC) return;
    int g = tid >> 7;
    int c = gcnt[g];
    out[tid] = gsum[tid] * ((c > 1) ? (1.0f / (float)c) : 1.0f);
}

// ---------------- launcher ----------------
extern "C" void kernel_launch(void* const* d_in, const int* in_sizes, int n_in,
                              void* d_out, int out_size, void* d_ws, size_t ws_size,
                              hipStream_t stream) {
    const float* x        = (const float*)d_in[0];
    const float* edge_attr= (const float*)d_in[1];
    const float* W_emb    = (const float*)d_in[2];
    const float* b_emb    = (const float*)d_in[3];
    const float* Ws       = (const float*)d_in[4];
    const float* att_src  = (const float*)d_in[5];
    const float* att_dst  = (const float*)d_in[6];
    const float* att_edge = (const float*)d_in[7];
    const float* W_edge   = (const float*)d_in[8];
    const float* bias     = (const float*)d_in[9];
    const float* bn_gamma = (const float*)d_in[10];
    const float* bn_beta  = (const float*)d_in[11];
    const float* bn_mean  = (const float*)d_in[12];
    const float* bn_var   = (const float*)d_in[13];
    const float* W_out    = (const float*)d_in[14];
    const float* b_out    = (const float*)d_in[15];
    const int*   srcp     = (const int*)d_in[16];
    const int*   dstp     = srcp + NE;
    const int*   batch    = (const int*)d_in[17];
    float* out = (float*)d_out;

    char* wsb = (char*)d_ws;
    size_t off = 0;
    auto alloc = [&](size_t bytes) -> void* {
        void* p = (void*)(wsb + off);
        off += (bytes + 255) & ~(size_t)255;
        return p;
    };
    float* h0    = (float*)alloc((size_t)NN * DH * 4);
    float* h1    = (float*)alloc((size_t)NN * DH * 4);
    float* S     = (float*)alloc((size_t)NN * 20 * 4);
    float* a_e   = (float*)alloc((size_t)E2 * NHD * 4);
    float* loop  = (float*)alloc((size_t)NN * DE * 4);
    int*   cnt   = (int*)alloc((size_t)NN * 4);
    int*   rp    = (int*)alloc((size_t)(NN + 1) * 4);
    int*   cursor= (int*)alloc((size_t)NN * 4);
    int*   eidx  = (int*)alloc((size_t)E2 * 4);
    int*   bsum  = (int*)alloc((size_t)SCAN_NB * 4);
    float* Wcomb = (float*)alloc((size_t)DH * 20 * 4);
    float* We    = (float*)alloc((size_t)DE * NHD * 4);
    unsigned short* Bt = (unsigned short*)alloc((size_t)DH * 640 * 2);
    float* gsum  = (float*)alloc((size_t)NG * DOUTC * 4);
    int*   gcnt  = (int*)alloc((size_t)NG * 4);

    hipMemsetAsync(loop,   0, (size_t)NN * DE * 4, stream);
    hipMemsetAsync(cnt,    0, (size_t)NN * 4, stream);
    hipMemsetAsync(cursor, 0, (size_t)NN * 4, stream);
    hipMemsetAsync(gsum,   0, (size_t)NG * DOUTC * 4, stream);
    hipMemsetAsync(gcnt,   0, (size_t)NG * 4, stream);

    // preprocessing: self-loop attrs + dst-CSR
    k_loop_acc<<<(NE * DE + 255) / 256, 256, 0, stream>>>(dstp, edge_attr, loop, cnt);
    k_loop_div<<<(NN * DE + 255) / 256, 256, 0, stream>>>(loop, cnt);
    k_scan_a<<<SCAN_NB, SCAN_B, 0, stream>>>(cnt, bsum);
    k_scan_b<<<1, 64, 0, stream>>>(bsum);
    k_scan_c<<<SCAN_NB, SCAN_B, 0, stream>>>(cnt, bsum, rp);
    k_csr_fill<<<(E2 + 255) / 256, 256, 0, stream>>>(dstp, rp, cursor, eidx);

    // embedding
    k_emb<<<(NN + 3) / 4, 256, 0, stream>>>(x, W_emb, b_emb, h0);

    float* hb[2] = {h0, h1};
    for (int l = 0; l < NL; ++l) {
        float* hin  = hb[l & 1];
        float* hout = hb[(l + 1) & 1];
        k_comb<<<6, 256, 0, stream>>>(Ws, att_src, att_dst, W_edge, att_edge, Wcomb, We, l);
        k_prepB<<<(DH * 640 + 255) / 256, 256, 0, stream>>>(Ws, Bt, l);
        k_scores<<<(NN * 20 + 255) / 256, 256, 0, stream>>>(hin, Wcomb, S);
        k_ae<<<(E2 * NHD + 255) / 256, 256, 0, stream>>>(edge_attr, loop, We, a_e);
        k_layer<<<(NN + 31) / 32, 256, 0, stream>>>(S, a_e, hin, rp, eidx, srcp, Bt,
                                                    bias + l * DH, bn_gamma + l * DH,
                                                    bn_beta + l * DH, bn_mean + l * DH,
                                                    bn_var + l * DH, hout);
    }
    float* hfin = hb[NL & 1];

    // readout
    k_gcnt<<<(NN + 255) / 256, 256, 0, stream>>>(batch, gcnt);
    k_out<<<(NN + OUT_NODES - 1) / OUT_NODES, 128, 0, stream>>>(hfin, W_out, b_out, batch, gsum);
    k_fin<<<(NG * DOUTC + 255) / 256, 256, 0, stream>>>(gsum, gcnt, out);
}

// Round 3
// 486.659 us; speedup vs baseline: 1.6296x; 1.3255x over previous
//
#include <hip/hip_runtime.h>
#include <math.h>

// ---------------- problem constants ----------------
constexpr int NN   = 50000;          // nodes
constexpr int NE   = 150000;         // edges
constexpr int DIN  = 48;
constexpr int DH   = 64;
constexpr int DE   = 16;
constexpr int NHD  = 10;             // heads
constexpr int NL   = 3;              // layers
constexpr int DOUTC= 128;
constexpr int NG   = 4096;           // graphs
constexpr int E2   = NE + NN;        // edges incl self loops
constexpr int SCAN_B  = 256;
constexpr int SCAN_NB = (NN + SCAN_B - 1) / SCAN_B;   // 196

typedef __bf16 v8bf __attribute__((ext_vector_type(8)));
typedef short  v8s  __attribute__((ext_vector_type(8)));
typedef float  v4f  __attribute__((ext_vector_type(4)));

__device__ inline unsigned short f2bf(float f) {
    unsigned u = __builtin_bit_cast(unsigned, f);
    unsigned r = (u + 0x7FFFu + ((u >> 16) & 1u)) >> 16;
    return (unsigned short)r;
}

// ---------------- preprocessing ----------------
__global__ void k_cnt(const int* __restrict__ dst, int* __restrict__ cnt) {
    int e = blockIdx.x * blockDim.x + threadIdx.x;
    if (e < NE) atomicAdd(&cnt[dst[e]], 1);
}

__global__ void k_scan_a(const int* __restrict__ cnt, int* __restrict__ bsum) {
    __shared__ int s[SCAN_B];
    int i = blockIdx.x * SCAN_B + threadIdx.x;
    s[threadIdx.x] = (i < NN) ? (cnt[i] + 1) : 0;   // +1 = self loop
    __syncthreads();
    for (int off = SCAN_B / 2; off > 0; off >>= 1) {
        if (threadIdx.x < off) s[threadIdx.x] += s[threadIdx.x + off];
        __syncthreads();
    }
    if (threadIdx.x == 0) bsum[blockIdx.x] = s[0];
}

__global__ void k_scan_b(int* __restrict__ bsum) {
    if (threadIdx.x == 0 && blockIdx.x == 0) {
        int acc = 0;
        for (int i = 0; i < SCAN_NB; ++i) { int v = bsum[i]; bsum[i] = acc; acc += v; }
    }
}

__global__ void k_scan_c(const int* __restrict__ cnt, const int* __restrict__ bsum,
                         int* __restrict__ rp) {
    __shared__ int s[SCAN_B];
    int i = blockIdx.x * SCAN_B + threadIdx.x;
    int v = (i < NN) ? (cnt[i] + 1) : 0;
    s[threadIdx.x] = v;
    __syncthreads();
    for (int off = 1; off < SCAN_B; off <<= 1) {
        int t = (threadIdx.x >= off) ? s[threadIdx.x - off] : 0;
        __syncthreads();
        s[threadIdx.x] += t;
        __syncthreads();
    }
    if (i < NN) {
        int excl = bsum[blockIdx.x] + s[threadIdx.x] - v;
        rp[i] = excl;
        if (i == NN - 1) rp[NN] = excl + v;
    }
}

__global__ void k_csr_fill(const int* __restrict__ src, const int* __restrict__ dst,
                           const int* __restrict__ rp, int* __restrict__ cursor,
                           int* __restrict__ eidx, int* __restrict__ scsr,
                           int* __restrict__ dcsr) {
    int e = blockIdx.x * blockDim.x + threadIdx.x;
    if (e >= E2) return;
    int d  = (e < NE) ? dst[e] : (e - NE);
    int sn = (e < NE) ? src[e] : d;
    int pos = atomicAdd(&cursor[d], 1);
    int s = rp[d] + pos;
    eidx[s] = e; scsr[s] = sn; dcsr[s] = d;
}

// self-loop attr = mean of real incoming edge attrs (no atomics, via CSR)
__global__ void k_loopattr(const int* __restrict__ rp, const int* __restrict__ eidx,
                           const int* __restrict__ cnt, const float* __restrict__ ea,
                           float* __restrict__ loop) {
    int tid = blockIdx.x * blockDim.x + threadIdx.x;
    if (tid >= NN * DE) return;
    int n = tid >> 4, d = tid & 15;
    int r0 = rp[n], r1 = rp[n + 1];
    float s = 0.f;
    for (int t = r0; t < r1; ++t) {
        int eid = eidx[t];
        if (eid < NE) s += ea[(size_t)eid * DE + d];
    }
    int c = cnt[n];
    loop[tid] = s * ((c > 1) ? (1.0f / (float)c) : 1.0f);
}

// ---------------- embedding GEMM: h = x @ W_emb + b ----------------
__global__ void k_emb(const float* __restrict__ x, const float* __restrict__ W,
                      const float* __restrict__ b, float* __restrict__ h) {
    __shared__ float Wl[DIN * DH];
    for (int i = threadIdx.x; i < DIN * DH; i += blockDim.x) Wl[i] = W[i];
    __syncthreads();
    int n = blockIdx.x * (blockDim.x / DH) + threadIdx.x / DH;
    int c = threadIdx.x & (DH - 1);
    if (n >= NN) return;
    const float* xr = x + (size_t)n * DIN;
    float acc = b[c];
#pragma unroll
    for (int k = 0; k < DIN; ++k) acc += xr[k] * Wl[k * DH + c];
    h[(size_t)n * DH + c] = acc;
}

// ---------------- all-layer combined attention weights ----------------
__global__ void k_comb3(const float* __restrict__ Ws, const float* __restrict__ asrc,
                        const float* __restrict__ adst, const float* __restrict__ We_in,
                        const float* __restrict__ aedge, float* __restrict__ Wcomb,
                        float* __restrict__ We) {
    int layer = blockIdx.y;
    int tid = blockIdx.x * blockDim.x + threadIdx.x;
    if (tid < DH * 2 * NHD) {                      // 1280
        int k = tid / 20, j = tid % 20;
        int hh = j % NHD;
        const float* a = ((j < NHD) ? asrc : adst) + (size_t)layer * NHD * DH + hh * DH;
        const float* w = Ws + ((size_t)layer * DH + k) * (NHD * DH) + hh * DH;
        float s = 0.f;
#pragma unroll
        for (int f = 0; f < DH; ++f) s += w[f] * a[f];
        Wcomb[layer * 1280 + tid] = s;
    } else if (tid < DH * 2 * NHD + DE * NHD) {    // +160
        int t = tid - DH * 2 * NHD;
        int d = t / NHD, hh = t % NHD;
        const float* a = aedge + (size_t)layer * NHD * DH + hh * DH;
        const float* w = We_in + ((size_t)layer * DE + d) * (NHD * DH) + hh * DH;
        float s = 0.f;
#pragma unroll
        for (int f = 0; f < DH; ++f) s += w[f] * a[f];
        We[layer * 160 + t] = s;
    }
}

// ---------------- Bt[l][f][j] = Ws[l][j&63][(j>>6)*64 + f] * 0.1, bf16 ----------------
__global__ void k_prepB3(const float* __restrict__ Ws, unsigned short* __restrict__ Bt) {
    int layer = blockIdx.y;
    int tid = blockIdx.x * blockDim.x + threadIdx.x;
    if (tid >= DH * 640) return;
    int f = tid / 640, j = tid % 640;
    int hh = j >> 6, k = j & 63;
    float v = Ws[(size_t)layer * DH * 640 + (size_t)k * 640 + hh * 64 + f] * 0.1f;
    Bt[(size_t)layer * DH * 640 + tid] = f2bf(v);
}

// ---------------- S[n][0..9]=a_s, S[n][10..19]=a_d (layer 0 only) ----------------
__global__ void k_scores(const float* __restrict__ h, const float* __restrict__ Wcomb,
                         float* __restrict__ S) {
    __shared__ float wl[DH * 20];
    for (int i = threadIdx.x; i < DH * 20; i += blockDim.x) wl[i] = Wcomb[i];
    __syncthreads();
    int tid = blockIdx.x * blockDim.x + threadIdx.x;
    if (tid >= NN * 20) return;
    int n = tid / 20, j = tid % 20;
    const float* hr = h + (size_t)n * DH;
    float s = 0.f;
#pragma unroll 16
    for (int k = 0; k < DH; ++k) s += hr[k] * wl[k * 20 + j];
    S[tid] = s;
}

// ---------------- a_e for all 3 layers ----------------
__global__ void k_ae3(const float* __restrict__ ea, const float* __restrict__ loop,
                      const float* __restrict__ WeAll, float* __restrict__ aeAll) {
    int l = blockIdx.y;
    __shared__ float wl[DE * NHD];
    if (threadIdx.x < DE * NHD) wl[threadIdx.x] = WeAll[l * DE * NHD + threadIdx.x];
    __syncthreads();
    int tid = blockIdx.x * blockDim.x + threadIdx.x;
    if (tid >= E2 * NHD) return;
    int e = tid / NHD, hh = tid % NHD;
    const float* ar = (e < NE) ? (ea + (size_t)e * DE) : (loop + (size_t)(e - NE) * DE);
    float s = 0.f;
#pragma unroll
    for (int d = 0; d < DE; ++d) s += ar[d] * wl[d * NHD + hh];
    aeAll[(size_t)l * E2 * NHD + tid] = s;
}

// ---------------- alpha per CSR slot (edge-parallel, leaky_relu folded) ----------------
__global__ void k_alpha(const float* __restrict__ S, const float* __restrict__ ae,
                        const int* __restrict__ scsr, const int* __restrict__ dcsr,
                        const int* __restrict__ eidx, float* __restrict__ alpha) {
    int tid = blockIdx.x * blockDim.x + threadIdx.x;
    if (tid >= E2 * NHD) return;
    int s = tid / NHD, h = tid % NHD;
    int sn = scsr[s], dn = dcsr[s], eid = eidx[s];
    float a = S[(size_t)sn * 20 + h] + S[(size_t)dn * 20 + 10 + h]
            + ae[(size_t)eid * NHD + h];
    alpha[tid] = (a > 0.f) ? a : 0.2f * a;
}

// ---------------- fused layer: softmax-agg (LDS G tile) + MFMA GEMM + epilogue + next-S ----------------
// 512 threads = 8 waves, 32 nodes/block; wave w owns local nodes w*4..w*4+3 (Phase A).
constexpr int CE = 6;   // edges per chunk (60 lanes = 6 edges x 10 heads)
__global__ __launch_bounds__(512) void k_layer(
        const float* __restrict__ alpha, const float* __restrict__ hin,
        const int* __restrict__ rp, const int* __restrict__ scsr,
        const unsigned short* __restrict__ Bt, const float* __restrict__ Wcn,
        float* __restrict__ Sout, int do_s,
        const float* __restrict__ bias, const float* __restrict__ gam,
        const float* __restrict__ bet, const float* __restrict__ mean,
        const float* __restrict__ var, float* __restrict__ hout) {
    __shared__ __align__(16) unsigned short Gl[32][648];  // 41.5 KB
    __shared__ float ach[8][CE][NHD];
    __shared__ float pch[8][CE][NHD];
    __shared__ int   snl[8][CE];
    __shared__ float zil[8][NHD];
    __shared__ float Wcl[DH * 20];

    const int tid = threadIdx.x;
    const int w = tid >> 6, lane = tid & 63;
    const int blk = blockIdx.x;
    const int el = lane / NHD;        // 0..6
    const int hh = lane % NHD;

    if (do_s) for (int i = tid; i < DH * 20; i += 512) Wcl[i] = Wcn[i];

    // ---------------- Phase A ----------------
    for (int i = 0; i < 4; ++i) {
        const int local = w * 4 + i;
        const int n = blk * 32 + local;
        float g[NHD];
#pragma unroll
        for (int q = 0; q < NHD; ++q) g[q] = 0.f;
        float m = -1e30f, z = 0.f;

        if (n < NN) {
            const int r0 = rp[n], deg = rp[n + 1] - r0;
            // pass 1: stage alpha (one coalesced 240B load) + max
            for (int c0 = 0; c0 < deg; c0 += CE) {
                int ce = deg - c0; if (ce > CE) ce = CE;
                if (el < ce) {
                    ach[w][el][hh] = alpha[(size_t)(r0 + c0 + el) * NHD + hh];
                    if (hh == 0) snl[w][el] = scsr[r0 + c0 + el];
                }
                __builtin_amdgcn_wave_barrier();
                if (lane < NHD)
                    for (int j = 0; j < ce; ++j) m = fmaxf(m, ach[w][j][lane]);
                __builtin_amdgcn_wave_barrier();
            }
            // pass 2: exp/z + unnormalized accumulate (normalize by 1/z at end)
            for (int c0 = 0; c0 < deg; c0 += CE) {
                int ce = deg - c0; if (ce > CE) ce = CE;
                if (deg > CE) {                 // deg<=CE: ach/snl still valid from pass 1
                    if (el < ce) {
                        ach[w][el][hh] = alpha[(size_t)(r0 + c0 + el) * NHD + hh];
                        if (hh == 0) snl[w][el] = scsr[r0 + c0 + el];
                    }
                    __builtin_amdgcn_wave_barrier();
                }
                if (lane < NHD) {
                    for (int j = 0; j < ce; ++j) {
                        float p = __expf(ach[w][j][lane] - m);
                        z += p;
                        pch[w][j][lane] = p;
                    }
                }
                __builtin_amdgcn_wave_barrier();
                // batch the src-row gathers: issue all loads, then consume
                int sreg[CE];
#pragma unroll
                for (int j = 0; j < CE; ++j) sreg[j] = snl[w][(j < ce) ? j : 0];
                float hv[CE];
#pragma unroll
                for (int j = 0; j < CE; ++j)
                    hv[j] = (j < ce) ? hin[(size_t)sreg[j] * DH + lane] : 0.f;
#pragma unroll
                for (int j = 0; j < CE; ++j) {
                    if (j < ce) {
#pragma unroll
                        for (int q = 0; q < NHD; ++q) g[q] += pch[w][j][q] * hv[j];
                    }
                }
                __builtin_amdgcn_wave_barrier();
            }
            if (lane < NHD) zil[w][lane] = 1.f / z;
        }
        __builtin_amdgcn_wave_barrier();
#pragma unroll
        for (int q = 0; q < NHD; ++q) {
            float val = (n < NN) ? g[q] * zil[w][q] : 0.f;
            Gl[local][q * 64 + lane] = f2bf(val);
        }
        __builtin_amdgcn_wave_barrier();
    }

    __syncthreads();

    // ---------------- Phase B: xc = G @ B, one 16x16 MFMA tile per wave ----------------
    const int rt = w & 1;             // row tile (16 nodes)
    const int ct = w >> 1;            // col tile (16 features)
    const int la = lane & 15, lb = lane >> 4;
    v4f acc = {0.f, 0.f, 0.f, 0.f};
    const size_t brow = (size_t)(ct * 16 + la) * 640;
#pragma unroll 5
    for (int t = 0; t < 20; ++t) {
        const int koff = t * 32 + lb * 8;
        v8s av = *(const v8s*)&Gl[rt * 16 + la][koff];
        v8s bv = *(const v8s*)&Bt[brow + koff];
        acc = __builtin_amdgcn_mfma_f32_16x16x32_bf16(
                  __builtin_bit_cast(v8bf, av), __builtin_bit_cast(v8bf, bv), acc, 0, 0, 0);
    }
    __syncthreads();                  // Gl reads done; allow alias writes below

    // epilogue: bias + BN + gelu + residual; stash hout tile in LDS (alias Gl)
    float* hl = (float*)&Gl[0][0];    // [32][64] floats = 8 KB < 41.5 KB
    const int f = ct * 16 + la;
    const float bi = bias[f], gm = gam[f], bt_ = bet[f], mu = mean[f];
    const float iv = rsqrtf(var[f] + 1e-5f);
#pragma unroll
    for (int r = 0; r < 4; ++r) {
        const int local = rt * 16 + lb * 4 + r;
        const int n = blk * 32 + local;
        float hvold = (n < NN) ? hin[(size_t)n * DH + f] : 0.f;
        float v = acc[r] + bi;
        v = (v - mu) * gm * iv + bt_;
        v = 0.5f * v * (1.0f + erff(v * 0.70710678118654752f));
        float hnew = hvold + v;
        if (n < NN) hout[(size_t)n * DH + f] = hnew;
        hl[local * 64 + f] = hnew;
    }

    // fused next-layer scores: S[n][j] = hout[n] . Wcomb_next[:,j]
    if (do_s) {
        __syncthreads();
        for (int it = tid; it < 32 * 20; it += 512) {
            int local = it / 20, j = it % 20;
            int n = blk * 32 + local;
            if (n < NN) {
                const float* hr = &hl[local * 64];
                float s = 0.f;
#pragma unroll 16
                for (int k = 0; k < DH; ++k) s += hr[k] * Wcl[k * 20 + j];
                Sout[(size_t)n * 20 + j] = s;
            }
        }
    }
}

// ---------------- readout ----------------
__global__ void k_gcnt(const int* __restrict__ batch, int* __restrict__ gcnt) {
    int n = blockIdx.x * blockDim.x + threadIdx.x;
    if (n < NN) atomicAdd(&gcnt[batch[n]], 1);
}

constexpr int OUT_NODES = 64;
__global__ void k_out(const float* __restrict__ h, const float* __restrict__ W,
                      const float* __restrict__ b, const int* __restrict__ batch,
                      float* __restrict__ gsum) {
    __shared__ float Wl[DH * DOUTC];          // 32 KB
    __shared__ float hl[OUT_NODES][DH];       // 16 KB
    __shared__ int   bl[OUT_NODES];
    int n0 = blockIdx.x * OUT_NODES;
    for (int i = threadIdx.x; i < DH * DOUTC; i += 128) Wl[i] = W[i];
    for (int i = threadIdx.x; i < OUT_NODES * DH; i += 128) {
        int nn = n0 + (i >> 6);
        hl[i >> 6][i & 63] = (nn < NN) ? h[(size_t)nn * DH + (i & 63)] : 0.f;
    }
    if (threadIdx.x < OUT_NODES) {
        int nn = n0 + threadIdx.x;
        bl[threadIdx.x] = (nn < NN) ? batch[nn] : -1;
    }
    __syncthreads();
    int col = threadIdx.x;
    float acc = 0.f; int cur = -1;
    for (int t = 0; t < OUT_NODES; ++t) {
        if (n0 + t >= NN) break;
        float s = b[col];
#pragma unroll 16
        for (int k = 0; k < DH; ++k) s += hl[t][k] * Wl[k * DOUTC + col];
        int bg = bl[t];
        if (bg != cur) {
            if (cur >= 0) atomicAdd(&gsum[(size_t)cur * DOUTC + col], acc);
            cur = bg; acc = s;
        } else acc += s;
    }
    if (cur >= 0) atomicAdd(&gsum[(size_t)cur * DOUTC + col], acc);
}

__global__ void k_fin(const float* __restrict__ gsum, const int* __restrict__ gcnt,
                      float* __restrict__ out) {
    int tid = blockIdx.x * blockDim.x + threadIdx.x;
    if (tid >= NG * DOUTC) return;
    int g = tid >> 7;
    int c = gcnt[g];
    out[tid] = gsum[tid] * ((c > 1) ? (1.0f / (float)c) : 1.0f);
}

// ---------------- launcher ----------------
extern "C" void kernel_launch(void* const* d_in, const int* in_sizes, int n_in,
                              void* d_out, int out_size, void* d_ws, size_t ws_size,
                              hipStream_t stream) {
    const float* x        = (const float*)d_in[0];
    const float* edge_attr= (const float*)d_in[1];
    const float* W_emb    = (const float*)d_in[2];
    const float* b_emb    = (const float*)d_in[3];
    const float* Ws       = (const float*)d_in[4];
    const float* att_src  = (const float*)d_in[5];
    const float* att_dst  = (const float*)d_in[6];
    const float* att_edge = (const float*)d_in[7];
    const float* W_edge   = (const float*)d_in[8];
    const float* bias     = (const float*)d_in[9];
    const float* bn_gamma = (const float*)d_in[10];
    const float* bn_beta  = (const float*)d_in[11];
    const float* bn_mean  = (const float*)d_in[12];
    const float* bn_var   = (const float*)d_in[13];
    const float* W_out    = (const float*)d_in[14];
    const float* b_out    = (const float*)d_in[15];
    const int*   srcp     = (const int*)d_in[16];
    const int*   dstp     = srcp + NE;
    const int*   batch    = (const int*)d_in[17];
    float* out = (float*)d_out;

    char* wsb = (char*)d_ws;
    size_t off = 0;
    auto alloc = [&](size_t bytes) -> void* {
        void* p = (void*)(wsb + off);
        off += (bytes + 255) & ~(size_t)255;
        return p;
    };
    float* h0    = (float*)alloc((size_t)NN * DH * 4);
    float* h1    = (float*)alloc((size_t)NN * DH * 4);
    float* S     = (float*)alloc((size_t)NN * 20 * 4);
    float* aeAll = (float*)alloc((size_t)NL * E2 * NHD * 4);
    float* alpha = (float*)alloc((size_t)E2 * NHD * 4);
    float* loop  = (float*)alloc((size_t)NN * DE * 4);
    int*   cnt   = (int*)alloc((size_t)NN * 4);
    int*   rp    = (int*)alloc((size_t)(NN + 1) * 4);
    int*   cursor= (int*)alloc((size_t)NN * 4);
    int*   eidx  = (int*)alloc((size_t)E2 * 4);
    int*   scsr  = (int*)alloc((size_t)E2 * 4);
    int*   dcsr  = (int*)alloc((size_t)E2 * 4);
    int*   bsum  = (int*)alloc((size_t)SCAN_NB * 4);
    float* WcombA= (float*)alloc((size_t)NL * DH * 20 * 4);
    float* WeA   = (float*)alloc((size_t)NL * DE * NHD * 4);
    unsigned short* BtA = (unsigned short*)alloc((size_t)NL * DH * 640 * 2);
    float* gsum  = (float*)alloc((size_t)NG * DOUTC * 4);
    int*   gcnt  = (int*)alloc((size_t)NG * 4);

    hipMemsetAsync(cnt,    0, (size_t)NN * 4, stream);
    hipMemsetAsync(cursor, 0, (size_t)NN * 4, stream);
    hipMemsetAsync(gsum,   0, (size_t)NG * DOUTC * 4, stream);
    hipMemsetAsync(gcnt,   0, (size_t)NG * 4, stream);

    // preprocessing: CSR (eidx/scsr/dcsr) + self-loop attrs
    k_cnt<<<(NE + 255) / 256, 256, 0, stream>>>(dstp, cnt);
    k_scan_a<<<SCAN_NB, SCAN_B, 0, stream>>>(cnt, bsum);
    k_scan_b<<<1, 64, 0, stream>>>(bsum);
    k_scan_c<<<SCAN_NB, SCAN_B, 0, stream>>>(cnt, bsum, rp);
    k_csr_fill<<<(E2 + 255) / 256, 256, 0, stream>>>(srcp, dstp, rp, cursor, eidx, scsr, dcsr);
    k_loopattr<<<(NN * DE + 255) / 256, 256, 0, stream>>>(rp, eidx, cnt, edge_attr, loop);

    // embedding + per-layer constants
    k_emb<<<(NN + 3) / 4, 256, 0, stream>>>(x, W_emb, b_emb, h0);
    {
        dim3 g(6, NL);
        k_comb3<<<g, 256, 0, stream>>>(Ws, att_src, att_dst, W_edge, att_edge, WcombA, WeA);
    }
    {
        dim3 g((DH * 640 + 255) / 256, NL);
        k_prepB3<<<g, 256, 0, stream>>>(Ws, BtA);
    }
    {
        dim3 g((E2 * NHD + 255) / 256, NL);
        k_ae3<<<g, 256, 0, stream>>>(edge_attr, loop, WeA, aeAll);
    }
    k_scores<<<(NN * 20 + 255) / 256, 256, 0, stream>>>(h0, WcombA, S);

    float* hb[2] = {h0, h1};
    for (int l = 0; l < NL; ++l) {
        float* hin  = hb[l & 1];
        float* hout = hb[(l + 1) & 1];
        k_alpha<<<(E2 * NHD + 255) / 256, 256, 0, stream>>>(
            S, aeAll + (size_t)l * E2 * NHD, scsr, dcsr, eidx, alpha);
        k_layer<<<(NN + 31) / 32, 512, 0, stream>>>(
            alpha, hin, rp, scsr, BtA + (size_t)l * DH * 640,
            WcombA + (size_t)(l + 1 < NL ? l + 1 : 0) * DH * 20, S, (l + 1 < NL) ? 1 : 0,
            bias + l * DH, bn_gamma + l * DH, bn_beta + l * DH,
            bn_mean + l * DH, bn_var + l * DH, hout);
    }
    float* hfin = hb[NL & 1];

    // readout
    k_gcnt<<<(NN + 255) / 256, 256, 0, stream>>>(batch, gcnt);
    k_out<<<(NN + OUT_NODES - 1) / OUT_NODES, 128, 0, stream>>>(hfin, W_out, b_out, batch, gsum);
    k_fin<<<(NG * DOUTC + 255) / 256, 256, 0, stream>>>(gsum, gcnt, out);
}

// Round 4
// 394.614 us; speedup vs baseline: 2.0098x; 1.2333x over previous
//
#include <hip/hip_runtime.h>
#include <math.h>

// ---------------- problem constants ----------------
constexpr int NN   = 50000;          // nodes
constexpr int NE   = 150000;         // edges
constexpr int DIN  = 48;
constexpr int DH   = 64;
constexpr int DE   = 16;
constexpr int NHD  = 10;             // heads
constexpr int NL   = 3;              // layers
constexpr int DOUTC= 128;
constexpr int NG   = 4096;           // graphs
constexpr int E2   = NE + NN;        // edges incl self loops
constexpr int SCAN_B  = 256;
constexpr int SCAN_NB = (NN + SCAN_B - 1) / SCAN_B;   // 196

typedef __bf16 v8bf __attribute__((ext_vector_type(8)));
typedef short  v8s  __attribute__((ext_vector_type(8)));
typedef float  v4f  __attribute__((ext_vector_type(4)));

__device__ inline unsigned short f2bf(float f) {
    unsigned u = __builtin_bit_cast(unsigned, f);
    unsigned r = (u + 0x7FFFu + ((u >> 16) & 1u)) >> 16;
    return (unsigned short)r;
}

// ---------------- preprocessing ----------------
__global__ void k_cnt(const int* __restrict__ dst, int* __restrict__ cnt) {
    int e = blockIdx.x * blockDim.x + threadIdx.x;
    if (e < NE) atomicAdd(&cnt[dst[e]], 1);
}

__global__ void k_scan_a(const int* __restrict__ cnt, int* __restrict__ bsum) {
    __shared__ int s[SCAN_B];
    int i = blockIdx.x * SCAN_B + threadIdx.x;
    s[threadIdx.x] = (i < NN) ? (cnt[i] + 1) : 0;   // +1 = self loop
    __syncthreads();
    for (int off = SCAN_B / 2; off > 0; off >>= 1) {
        if (threadIdx.x < off) s[threadIdx.x] += s[threadIdx.x + off];
        __syncthreads();
    }
    if (threadIdx.x == 0) bsum[blockIdx.x] = s[0];
}

__global__ void k_scan_b(int* __restrict__ bsum) {
    if (threadIdx.x == 0 && blockIdx.x == 0) {
        int acc = 0;
        for (int i = 0; i < SCAN_NB; ++i) { int v = bsum[i]; bsum[i] = acc; acc += v; }
    }
}

__global__ void k_scan_c(const int* __restrict__ cnt, const int* __restrict__ bsum,
                         int* __restrict__ rp) {
    __shared__ int s[SCAN_B];
    int i = blockIdx.x * SCAN_B + threadIdx.x;
    int v = (i < NN) ? (cnt[i] + 1) : 0;
    s[threadIdx.x] = v;
    __syncthreads();
    for (int off = 1; off < SCAN_B; off <<= 1) {
        int t = (threadIdx.x >= off) ? s[threadIdx.x - off] : 0;
        __syncthreads();
        s[threadIdx.x] += t;
        __syncthreads();
    }
    if (i < NN) {
        int excl = bsum[blockIdx.x] + s[threadIdx.x] - v;
        rp[i] = excl;
        if (i == NN - 1) rp[NN] = excl + v;
    }
}

__global__ void k_csr_fill(const int* __restrict__ src, const int* __restrict__ dst,
                           const int* __restrict__ rp, int* __restrict__ cursor,
                           int* __restrict__ eidx, int* __restrict__ scsr,
                           int* __restrict__ dcsr) {
    int e = blockIdx.x * blockDim.x + threadIdx.x;
    if (e >= E2) return;
    int d  = (e < NE) ? dst[e] : (e - NE);
    int sn = (e < NE) ? src[e] : d;
    int pos = atomicAdd(&cursor[d], 1);
    int s = rp[d] + pos;
    eidx[s] = e; scsr[s] = sn; dcsr[s] = d;
}

// self-loop attr = mean of real incoming edge attrs (no atomics, via CSR)
__global__ void k_loopattr(const int* __restrict__ rp, const int* __restrict__ eidx,
                           const int* __restrict__ cnt, const float* __restrict__ ea,
                           float* __restrict__ loop) {
    int tid = blockIdx.x * blockDim.x + threadIdx.x;
    if (tid >= NN * DE) return;
    int n = tid >> 4, d = tid & 15;
    int r0 = rp[n], r1 = rp[n + 1];
    float s = 0.f;
    for (int t = r0; t < r1; ++t) {
        int eid = eidx[t];
        if (eid < NE) s += ea[(size_t)eid * DE + d];
    }
    int c = cnt[n];
    loop[tid] = s * ((c > 1) ? (1.0f / (float)c) : 1.0f);
}

// graph row pointers from sorted batch ids
__global__ void k_grp(const int* __restrict__ batch, int* __restrict__ grp) {
    int n = blockIdx.x * blockDim.x + threadIdx.x;
    if (n >= NN) return;
    int b = batch[n];
    int pb = (n == 0) ? -1 : batch[n - 1];
    for (int g = pb + 1; g <= b; ++g) grp[g] = n;
    if (n == NN - 1) for (int g = b + 1; g <= NG; ++g) grp[g] = NN;
}

// ---------------- embedding GEMM + fused layer-0 scores ----------------
__global__ __launch_bounds__(256) void k_emb(const float* __restrict__ x,
        const float* __restrict__ W, const float* __restrict__ b,
        const float* __restrict__ Wc, float* __restrict__ h, float* __restrict__ S) {
    __shared__ float Wl[DIN * DH];      // 12 KB
    __shared__ float Wcl[DH * 20];      // 5 KB
    __shared__ float hl[4][DH];         // 1 KB
    for (int i = threadIdx.x; i < DIN * DH; i += 256) Wl[i] = W[i];
    for (int i = threadIdx.x; i < DH * 20; i += 256) Wcl[i] = Wc[i];
    __syncthreads();
    int w = threadIdx.x >> 6, c = threadIdx.x & 63;
    int n = blockIdx.x * 4 + w;
    float acc = b[c];
    if (n < NN) {
        const float* xr = x + (size_t)n * DIN;
#pragma unroll
        for (int k = 0; k < DIN; ++k) acc += xr[k] * Wl[k * DH + c];
        h[(size_t)n * DH + c] = acc;
    }
    hl[w][c] = acc;
    __syncthreads();
    if (threadIdx.x < 4 * 20) {
        int wi = threadIdx.x / 20, j = threadIdx.x % 20;
        int nn = blockIdx.x * 4 + wi;
        if (nn < NN) {
            const float* hr = hl[wi];
            float s = 0.f;
#pragma unroll 16
            for (int k = 0; k < DH; ++k) s += hr[k] * Wcl[k * 20 + j];
            S[(size_t)nn * 20 + j] = s;
        }
    }
}

// ---------------- all-layer combined attention weights ----------------
__global__ void k_comb3(const float* __restrict__ Ws, const float* __restrict__ asrc,
                        const float* __restrict__ adst, const float* __restrict__ We_in,
                        const float* __restrict__ aedge, float* __restrict__ Wcomb,
                        float* __restrict__ We) {
    int layer = blockIdx.y;
    int tid = blockIdx.x * blockDim.x + threadIdx.x;
    if (tid < DH * 2 * NHD) {                      // 1280
        int k = tid / 20, j = tid % 20;
        int hh = j % NHD;
        const float* a = ((j < NHD) ? asrc : adst) + (size_t)layer * NHD * DH + hh * DH;
        const float* w = Ws + ((size_t)layer * DH + k) * (NHD * DH) + hh * DH;
        float s = 0.f;
#pragma unroll
        for (int f = 0; f < DH; ++f) s += w[f] * a[f];
        Wcomb[layer * 1280 + tid] = s;
    } else if (tid < DH * 2 * NHD + DE * NHD) {    // +160
        int t = tid - DH * 2 * NHD;
        int d = t / NHD, hh = t % NHD;
        const float* a = aedge + (size_t)layer * NHD * DH + hh * DH;
        const float* w = We_in + ((size_t)layer * DE + d) * (NHD * DH) + hh * DH;
        float s = 0.f;
#pragma unroll
        for (int f = 0; f < DH; ++f) s += w[f] * a[f];
        We[layer * 160 + t] = s;
    }
}

// ---------------- Bt[l][f][j] = Ws[l][j&63][(j>>6)*64 + f] * 0.1, bf16 ----------------
__global__ void k_prepB3(const float* __restrict__ Ws, unsigned short* __restrict__ Bt) {
    int layer = blockIdx.y;
    int tid = blockIdx.x * blockDim.x + threadIdx.x;
    if (tid >= DH * 640) return;
    int f = tid / 640, j = tid % 640;
    int hh = j >> 6, k = j & 63;
    float v = Ws[(size_t)layer * DH * 640 + (size_t)k * 640 + hh * 64 + f] * 0.1f;
    Bt[(size_t)layer * DH * 640 + tid] = f2bf(v);
}

// ---------------- a_e for all 3 layers ----------------
__global__ void k_ae3(const float* __restrict__ ea, const float* __restrict__ loop,
                      const float* __restrict__ WeAll, float* __restrict__ aeAll) {
    int l = blockIdx.y;
    __shared__ float wl[DE * NHD];
    if (threadIdx.x < DE * NHD) wl[threadIdx.x] = WeAll[l * DE * NHD + threadIdx.x];
    __syncthreads();
    int tid = blockIdx.x * blockDim.x + threadIdx.x;
    if (tid >= E2 * NHD) return;
    int e = tid / NHD, hh = tid % NHD;
    const float* ar = (e < NE) ? (ea + (size_t)e * DE) : (loop + (size_t)(e - NE) * DE);
    float s = 0.f;
#pragma unroll
    for (int d = 0; d < DE; ++d) s += ar[d] * wl[d * NHD + hh];
    aeAll[(size_t)l * E2 * NHD + tid] = s;
}

// ---------------- alpha per CSR slot (edge-parallel, leaky_relu folded) ----------------
__global__ void k_alpha(const float* __restrict__ S, const float* __restrict__ ae,
                        const int* __restrict__ scsr, const int* __restrict__ dcsr,
                        const int* __restrict__ eidx, float* __restrict__ alpha) {
    int tid = blockIdx.x * blockDim.x + threadIdx.x;
    if (tid >= E2 * NHD) return;
    int s = tid / NHD, h = tid % NHD;
    int sn = scsr[s], dn = dcsr[s], eid = eidx[s];
    float a = S[(size_t)sn * 20 + h] + S[(size_t)dn * 20 + 10 + h]
            + ae[(size_t)eid * NHD + h];
    alpha[tid] = (a > 0.f) ? a : 0.2f * a;
}

// ---------------- fused layer: softmax-agg (LDS G tile) + MFMA GEMM + epilogue + next-S ----------------
// 512 threads = 8 waves, 32 nodes/block; wave w owns local nodes w*4..w*4+3 (Phase A).
constexpr int CE = 6;   // edges per chunk (60 lanes = 6 edges x 10 heads)
__global__ __launch_bounds__(512) void k_layer(
        const float* __restrict__ alpha, const float* __restrict__ hin,
        const int* __restrict__ rp, const int* __restrict__ scsr,
        const unsigned short* __restrict__ Bt, const float* __restrict__ Wcn,
        float* __restrict__ Sout, int do_s,
        const float* __restrict__ bias, const float* __restrict__ gam,
        const float* __restrict__ bet, const float* __restrict__ mean,
        const float* __restrict__ var, float* __restrict__ hout) {
    __shared__ __align__(16) unsigned short Gl[32][648];  // 41.5 KB
    __shared__ float ach[8][CE][NHD];
    __shared__ float pch[8][CE][NHD];
    __shared__ int   snl[8][CE];
    __shared__ float zil[8][NHD];
    __shared__ float Wcl[DH * 20];

    const int tid = threadIdx.x;
    const int w = tid >> 6, lane = tid & 63;
    const int blk = blockIdx.x;
    const int el = lane / NHD;        // 0..6
    const int hh = lane % NHD;

    if (do_s) for (int i = tid; i < DH * 20; i += 512) Wcl[i] = Wcn[i];

    // ---------------- Phase A ----------------
    for (int i = 0; i < 4; ++i) {
        const int local = w * 4 + i;
        const int n = blk * 32 + local;
        float g[NHD];
#pragma unroll
        for (int q = 0; q < NHD; ++q) g[q] = 0.f;
        float m = -1e30f, z = 0.f;

        if (n < NN) {
            const int r0 = rp[n], deg = rp[n + 1] - r0;
            // pass 1: stage alpha (one coalesced 240B load) + max
            for (int c0 = 0; c0 < deg; c0 += CE) {
                int ce = deg - c0; if (ce > CE) ce = CE;
                if (el < ce) {
                    ach[w][el][hh] = alpha[(size_t)(r0 + c0 + el) * NHD + hh];
                    if (hh == 0) snl[w][el] = scsr[r0 + c0 + el];
                }
                __builtin_amdgcn_wave_barrier();
                if (lane < NHD)
                    for (int j = 0; j < ce; ++j) m = fmaxf(m, ach[w][j][lane]);
                __builtin_amdgcn_wave_barrier();
            }
            // pass 2: exp/z + unnormalized accumulate (normalize by 1/z at end)
            for (int c0 = 0; c0 < deg; c0 += CE) {
                int ce = deg - c0; if (ce > CE) ce = CE;
                if (deg > CE) {                 // deg<=CE: ach/snl still valid from pass 1
                    if (el < ce) {
                        ach[w][el][hh] = alpha[(size_t)(r0 + c0 + el) * NHD + hh];
                        if (hh == 0) snl[w][el] = scsr[r0 + c0 + el];
                    }
                    __builtin_amdgcn_wave_barrier();
                }
                if (lane < NHD) {
                    for (int j = 0; j < ce; ++j) {
                        float p = __expf(ach[w][j][lane] - m);
                        z += p;
                        pch[w][j][lane] = p;
                    }
                }
                __builtin_amdgcn_wave_barrier();
                // batch the src-row gathers: issue all loads, then consume
                int sreg[CE];
#pragma unroll
                for (int j = 0; j < CE; ++j) sreg[j] = snl[w][(j < ce) ? j : 0];
                float hv[CE];
#pragma unroll
                for (int j = 0; j < CE; ++j)
                    hv[j] = (j < ce) ? hin[(size_t)sreg[j] * DH + lane] : 0.f;
#pragma unroll
                for (int j = 0; j < CE; ++j) {
                    if (j < ce) {
#pragma unroll
                        for (int q = 0; q < NHD; ++q) g[q] += pch[w][j][q] * hv[j];
                    }
                }
                __builtin_amdgcn_wave_barrier();
            }
            if (lane < NHD) zil[w][lane] = 1.f / z;
        }
        __builtin_amdgcn_wave_barrier();
#pragma unroll
        for (int q = 0; q < NHD; ++q) {
            float val = (n < NN) ? g[q] * zil[w][q] : 0.f;
            Gl[local][q * 64 + lane] = f2bf(val);
        }
        __builtin_amdgcn_wave_barrier();
    }

    __syncthreads();

    // ---------------- Phase B: xc = G @ B, one 16x16 MFMA tile per wave ----------------
    const int rt = w & 1;             // row tile (16 nodes)
    const int ct = w >> 1;            // col tile (16 features)
    const int la = lane & 15, lb = lane >> 4;
    v4f acc = {0.f, 0.f, 0.f, 0.f};
    const size_t brow = (size_t)(ct * 16 + la) * 640;
#pragma unroll 5
    for (int t = 0; t < 20; ++t) {
        const int koff = t * 32 + lb * 8;
        v8s av = *(const v8s*)&Gl[rt * 16 + la][koff];
        v8s bv = *(const v8s*)&Bt[brow + koff];
        acc = __builtin_amdgcn_mfma_f32_16x16x32_bf16(
                  __builtin_bit_cast(v8bf, av), __builtin_bit_cast(v8bf, bv), acc, 0, 0, 0);
    }
    __syncthreads();                  // Gl reads done; allow alias writes below

    // epilogue: bias + BN + gelu + residual; stash hout tile in LDS (alias Gl)
    float* hl = (float*)&Gl[0][0];    // [32][64] floats = 8 KB < 41.5 KB
    const int f = ct * 16 + la;
    const float bi = bias[f], gm = gam[f], bt_ = bet[f], mu = mean[f];
    const float iv = rsqrtf(var[f] + 1e-5f);
#pragma unroll
    for (int r = 0; r < 4; ++r) {
        const int local = rt * 16 + lb * 4 + r;
        const int n = blk * 32 + local;
        float hvold = (n < NN) ? hin[(size_t)n * DH + f] : 0.f;
        float v = acc[r] + bi;
        v = (v - mu) * gm * iv + bt_;
        v = 0.5f * v * (1.0f + erff(v * 0.70710678118654752f));
        float hnew = hvold + v;
        if (n < NN) hout[(size_t)n * DH + f] = hnew;
        hl[local * 64 + f] = hnew;
    }

    // fused next-layer scores: S[n][j] = hout[n] . Wcomb_next[:,j]
    if (do_s) {
        __syncthreads();
        for (int it = tid; it < 32 * 20; it += 512) {
            int local = it / 20, j = it % 20;
            int n = blk * 32 + local;
            if (n < NN) {
                const float* hr = &hl[local * 64];
                float s = 0.f;
#pragma unroll 16
                for (int k = 0; k < DH; ++k) s += hr[k] * Wcl[k * 20 + j];
                Sout[(size_t)n * 20 + j] = s;
            }
        }
    }
}

// ---------------- readout: out[g] = (segsum(h)[g] @ W_out + cnt*b_out) / max(cnt,1) ----------------
__global__ __launch_bounds__(256) void k_gout(const float* __restrict__ h,
        const float* __restrict__ W, const float* __restrict__ b,
        const int* __restrict__ grp, float* __restrict__ out) {
    __shared__ float Wl[DH * DOUTC];  // 32 KB
    __shared__ float hl[4][DH];
    __shared__ float cl[4];
    for (int i = threadIdx.x; i < DH * DOUTC; i += 256) Wl[i] = W[i];
    int w = threadIdx.x >> 6, lane = threadIdx.x & 63;
    int g = blockIdx.x * 4 + w;
    int r0 = grp[g], r1 = grp[g + 1];
    float s = 0.f;
    for (int n = r0; n < r1; ++n) s += h[(size_t)n * DH + lane];
    hl[w][lane] = s;
    if (lane == 0) cl[w] = (float)(r1 - r0);
    __syncthreads();
    for (int idx = threadIdx.x; idx < 4 * DOUTC; idx += 256) {
        int gi = idx >> 7, c = idx & 127;
        float cnt = cl[gi];
        float inv = 1.f / fmaxf(cnt, 1.f);
        float acc = cnt * b[c];
        const float* hr = hl[gi];
#pragma unroll 16
        for (int k = 0; k < DH; ++k) acc += hr[k] * Wl[k * DOUTC + c];
        out[(size_t)(blockIdx.x * 4 + gi) * DOUTC + c] = acc * inv;
    }
}

// ---------------- launcher ----------------
extern "C" void kernel_launch(void* const* d_in, const int* in_sizes, int n_in,
                              void* d_out, int out_size, void* d_ws, size_t ws_size,
                              hipStream_t stream) {
    const float* x        = (const float*)d_in[0];
    const float* edge_attr= (const float*)d_in[1];
    const float* W_emb    = (const float*)d_in[2];
    const float* b_emb    = (const float*)d_in[3];
    const float* Ws       = (const float*)d_in[4];
    const float* att_src  = (const float*)d_in[5];
    const float* att_dst  = (const float*)d_in[6];
    const float* att_edge = (const float*)d_in[7];
    const float* W_edge   = (const float*)d_in[8];
    const float* bias     = (const float*)d_in[9];
    const float* bn_gamma = (const float*)d_in[10];
    const float* bn_beta  = (const float*)d_in[11];
    const float* bn_mean  = (const float*)d_in[12];
    const float* bn_var   = (const float*)d_in[13];
    const float* W_out    = (const float*)d_in[14];
    const float* b_out    = (const float*)d_in[15];
    const int*   srcp     = (const int*)d_in[16];
    const int*   dstp     = srcp + NE;
    const int*   batch    = (const int*)d_in[17];
    float* out = (float*)d_out;

    char* wsb = (char*)d_ws;
    size_t off = 0;
    auto alloc = [&](size_t bytes) -> void* {
        void* p = (void*)(wsb + off);
        off += (bytes + 255) & ~(size_t)255;
        return p;
    };
    float* h0    = (float*)alloc((size_t)NN * DH * 4);
    float* h1    = (float*)alloc((size_t)NN * DH * 4);
    float* S     = (float*)alloc((size_t)NN * 20 * 4);
    float* aeAll = (float*)alloc((size_t)NL * E2 * NHD * 4);
    float* alpha = (float*)alloc((size_t)E2 * NHD * 4);
    float* loop  = (float*)alloc((size_t)NN * DE * 4);
    int*   cnt   = (int*)alloc((size_t)NN * 4);
    int*   rp    = (int*)alloc((size_t)(NN + 1) * 4);
    int*   cursor= (int*)alloc((size_t)NN * 4);
    int*   eidx  = (int*)alloc((size_t)E2 * 4);
    int*   scsr  = (int*)alloc((size_t)E2 * 4);
    int*   dcsr  = (int*)alloc((size_t)E2 * 4);
    int*   bsum  = (int*)alloc((size_t)SCAN_NB * 4);
    int*   grp   = (int*)alloc((size_t)(NG + 1) * 4);
    float* WcombA= (float*)alloc((size_t)NL * DH * 20 * 4);
    float* WeA   = (float*)alloc((size_t)NL * DE * NHD * 4);
    unsigned short* BtA = (unsigned short*)alloc((size_t)NL * DH * 640 * 2);

    hipMemsetAsync(cnt,    0, (size_t)NN * 4, stream);
    hipMemsetAsync(cursor, 0, (size_t)NN * 4, stream);

    // preprocessing: CSR (eidx/scsr/dcsr) + self-loop attrs + graph ptrs
    k_cnt<<<(NE + 255) / 256, 256, 0, stream>>>(dstp, cnt);
    k_scan_a<<<SCAN_NB, SCAN_B, 0, stream>>>(cnt, bsum);
    k_scan_b<<<1, 64, 0, stream>>>(bsum);
    k_scan_c<<<SCAN_NB, SCAN_B, 0, stream>>>(cnt, bsum, rp);
    k_csr_fill<<<(E2 + 255) / 256, 256, 0, stream>>>(srcp, dstp, rp, cursor, eidx, scsr, dcsr);
    k_loopattr<<<(NN * DE + 255) / 256, 256, 0, stream>>>(rp, eidx, cnt, edge_attr, loop);
    k_grp<<<(NN + 255) / 256, 256, 0, stream>>>(batch, grp);

    // per-layer constants
    {
        dim3 g(6, NL);
        k_comb3<<<g, 256, 0, stream>>>(Ws, att_src, att_dst, W_edge, att_edge, WcombA, WeA);
    }
    {
        dim3 g((DH * 640 + 255) / 256, NL);
        k_prepB3<<<g, 256, 0, stream>>>(Ws, BtA);
    }
    {
        dim3 g((E2 * NHD + 255) / 256, NL);
        k_ae3<<<g, 256, 0, stream>>>(edge_attr, loop, WeA, aeAll);
    }

    // embedding + fused layer-0 scores
    k_emb<<<(NN + 3) / 4, 256, 0, stream>>>(x, W_emb, b_emb, WcombA, h0, S);

    float* hb[2] = {h0, h1};
    for (int l = 0; l < NL; ++l) {
        float* hin  = hb[l & 1];
        float* hout = hb[(l + 1) & 1];
        k_alpha<<<(E2 * NHD + 255) / 256, 256, 0, stream>>>(
            S, aeAll + (size_t)l * E2 * NHD, scsr, dcsr, eidx, alpha);
        k_layer<<<(NN + 31) / 32, 512, 0, stream>>>(
            alpha, hin, rp, scsr, BtA + (size_t)l * DH * 640,
            WcombA + (size_t)(l + 1 < NL ? l + 1 : 0) * DH * 20, S, (l + 1 < NL) ? 1 : 0,
            bias + l * DH, bn_gamma + l * DH, bn_beta + l * DH,
            bn_mean + l * DH, bn_var + l * DH, hout);
    }
    float* hfin = hb[NL & 1];

    // readout
    k_gout<<<NG / 4, 256, 0, stream>>>(hfin, W_out, b_out, grp, out);
}

// Round 5
// 376.524 us; speedup vs baseline: 2.1063x; 1.0480x over previous
//
#include <hip/hip_runtime.h>
#include <math.h>

// ---------------- problem constants ----------------
constexpr int NN   = 50000;          // nodes
constexpr int NE   = 150000;         // edges
constexpr int DIN  = 48;
constexpr int DH   = 64;
constexpr int DE   = 16;
constexpr int NHD  = 10;             // heads
constexpr int NL   = 3;              // layers
constexpr int DOUTC= 128;
constexpr int NG   = 4096;           // graphs
constexpr int E2   = NE + NN;        // edges incl self loops
constexpr int SCAN_B  = 256;
constexpr int SCAN_NB = (NN + SCAN_B - 1) / SCAN_B;   // 196

typedef __bf16 v8bf __attribute__((ext_vector_type(8)));
typedef short  v8s  __attribute__((ext_vector_type(8)));
typedef float  v4f  __attribute__((ext_vector_type(4)));

__device__ inline unsigned short f2bf(float f) {
    unsigned u = __builtin_bit_cast(unsigned, f);
    unsigned r = (u + 0x7FFFu + ((u >> 16) & 1u)) >> 16;
    return (unsigned short)r;
}

// ---------------- preprocessing ----------------
__global__ void k_cnt(const int* __restrict__ dst, int* __restrict__ cnt) {
    int e = blockIdx.x * blockDim.x + threadIdx.x;
    if (e < NE) atomicAdd(&cnt[dst[e]], 1);
}

__global__ void k_scan_a(const int* __restrict__ cnt, int* __restrict__ bsum) {
    __shared__ int s[SCAN_B];
    int i = blockIdx.x * SCAN_B + threadIdx.x;
    s[threadIdx.x] = (i < NN) ? (cnt[i] + 1) : 0;   // +1 = self loop
    __syncthreads();
    for (int off = SCAN_B / 2; off > 0; off >>= 1) {
        if (threadIdx.x < off) s[threadIdx.x] += s[threadIdx.x + off];
        __syncthreads();
    }
    if (threadIdx.x == 0) bsum[blockIdx.x] = s[0];
}

__global__ void k_scan_b(int* __restrict__ bsum) {
    if (threadIdx.x == 0 && blockIdx.x == 0) {
        int acc = 0;
        for (int i = 0; i < SCAN_NB; ++i) { int v = bsum[i]; bsum[i] = acc; acc += v; }
    }
}

__global__ void k_scan_c(const int* __restrict__ cnt, const int* __restrict__ bsum,
                         int* __restrict__ rp) {
    __shared__ int s[SCAN_B];
    int i = blockIdx.x * SCAN_B + threadIdx.x;
    int v = (i < NN) ? (cnt[i] + 1) : 0;
    s[threadIdx.x] = v;
    __syncthreads();
    for (int off = 1; off < SCAN_B; off <<= 1) {
        int t = (threadIdx.x >= off) ? s[threadIdx.x - off] : 0;
        __syncthreads();
        s[threadIdx.x] += t;
        __syncthreads();
    }
    if (i < NN) {
        int excl = bsum[blockIdx.x] + s[threadIdx.x] - v;
        rp[i] = excl;
        if (i == NN - 1) rp[NN] = excl + v;
    }
}

__global__ void k_csr_fill(const int* __restrict__ src, const int* __restrict__ dst,
                           const int* __restrict__ rp, int* __restrict__ cursor,
                           int* __restrict__ eidx, int* __restrict__ scsr) {
    int e = blockIdx.x * blockDim.x + threadIdx.x;
    if (e >= E2) return;
    int d  = (e < NE) ? dst[e] : (e - NE);
    int sn = (e < NE) ? src[e] : d;
    int pos = atomicAdd(&cursor[d], 1);
    int s = rp[d] + pos;
    eidx[s] = e; scsr[s] = sn;
}

// self-loop attr = mean of real incoming edge attrs (no atomics, via CSR)
__global__ void k_loopattr(const int* __restrict__ rp, const int* __restrict__ eidx,
                           const int* __restrict__ cnt, const float* __restrict__ ea,
                           float* __restrict__ loop) {
    int tid = blockIdx.x * blockDim.x + threadIdx.x;
    if (tid >= NN * DE) return;
    int n = tid >> 4, d = tid & 15;
    int r0 = rp[n], r1 = rp[n + 1];
    float s = 0.f;
    for (int t = r0; t < r1; ++t) {
        int eid = eidx[t];
        if (eid < NE) s += ea[(size_t)eid * DE + d];
    }
    int c = cnt[n];
    loop[tid] = s * ((c > 1) ? (1.0f / (float)c) : 1.0f);
}

// graph row pointers from sorted batch ids
__global__ void k_grp(const int* __restrict__ batch, int* __restrict__ grp) {
    int n = blockIdx.x * blockDim.x + threadIdx.x;
    if (n >= NN) return;
    int b = batch[n];
    int pb = (n == 0) ? -1 : batch[n - 1];
    for (int g = pb + 1; g <= b; ++g) grp[g] = n;
    if (n == NN - 1) for (int g = b + 1; g <= NG; ++g) grp[g] = NN;
}

// ---------------- embedding GEMM + fused layer-0 scores ----------------
__global__ __launch_bounds__(256) void k_emb(const float* __restrict__ x,
        const float* __restrict__ W, const float* __restrict__ b,
        const float* __restrict__ Wc, float* __restrict__ h, float* __restrict__ S) {
    __shared__ float Wl[DIN * DH];      // 12 KB
    __shared__ float Wcl[DH * 20];      // 5 KB
    __shared__ float hl[4][DH];         // 1 KB
    for (int i = threadIdx.x; i < DIN * DH; i += 256) Wl[i] = W[i];
    for (int i = threadIdx.x; i < DH * 20; i += 256) Wcl[i] = Wc[i];
    __syncthreads();
    int w = threadIdx.x >> 6, c = threadIdx.x & 63;
    int n = blockIdx.x * 4 + w;
    float acc = b[c];
    if (n < NN) {
        const float* xr = x + (size_t)n * DIN;
#pragma unroll
        for (int k = 0; k < DIN; ++k) acc += xr[k] * Wl[k * DH + c];
        h[(size_t)n * DH + c] = acc;
    }
    hl[w][c] = acc;
    __syncthreads();
    if (threadIdx.x < 4 * 20) {
        int wi = threadIdx.x / 20, j = threadIdx.x % 20;
        int nn = blockIdx.x * 4 + wi;
        if (nn < NN) {
            const float* hr = hl[wi];
            float s = 0.f;
#pragma unroll 16
            for (int k = 0; k < DH; ++k) s += hr[k] * Wcl[k * 20 + j];
            S[(size_t)nn * 20 + j] = s;
        }
    }
}

// ---------------- all-layer combined attention weights ----------------
__global__ void k_comb3(const float* __restrict__ Ws, const float* __restrict__ asrc,
                        const float* __restrict__ adst, const float* __restrict__ We_in,
                        const float* __restrict__ aedge, float* __restrict__ Wcomb,
                        float* __restrict__ We) {
    int layer = blockIdx.y;
    int tid = blockIdx.x * blockDim.x + threadIdx.x;
    if (tid < DH * 2 * NHD) {                      // 1280
        int k = tid / 20, j = tid % 20;
        int hh = j % NHD;
        const float* a = ((j < NHD) ? asrc : adst) + (size_t)layer * NHD * DH + hh * DH;
        const float* w = Ws + ((size_t)layer * DH + k) * (NHD * DH) + hh * DH;
        float s = 0.f;
#pragma unroll
        for (int f = 0; f < DH; ++f) s += w[f] * a[f];
        Wcomb[layer * 1280 + tid] = s;
    } else if (tid < DH * 2 * NHD + DE * NHD) {    // +160
        int t = tid - DH * 2 * NHD;
        int d = t / NHD, hh = t % NHD;
        const float* a = aedge + (size_t)layer * NHD * DH + hh * DH;
        const float* w = We_in + ((size_t)layer * DE + d) * (NHD * DH) + hh * DH;
        float s = 0.f;
#pragma unroll
        for (int f = 0; f < DH; ++f) s += w[f] * a[f];
        We[layer * 160 + t] = s;
    }
}

// ---------------- Bt[l][f][j] = Ws[l][j&63][(j>>6)*64 + f] * 0.1, bf16 ----------------
__global__ void k_prepB3(const float* __restrict__ Ws, unsigned short* __restrict__ Bt) {
    int layer = blockIdx.y;
    int tid = blockIdx.x * blockDim.x + threadIdx.x;
    if (tid >= DH * 640) return;
    int f = tid / 640, j = tid % 640;
    int hh = j >> 6, k = j & 63;
    float v = Ws[(size_t)layer * DH * 640 + (size_t)k * 640 + hh * 64 + f] * 0.1f;
    Bt[(size_t)layer * DH * 640 + tid] = f2bf(v);
}

// ---------------- a_e in CSR slot order, all 3 layers ----------------
__global__ void k_aecsr(const float* __restrict__ ea, const float* __restrict__ loop,
                        const float* __restrict__ WeAll, const int* __restrict__ eidx,
                        float* __restrict__ aeAll) {
    int l = blockIdx.y;
    __shared__ float wl[DE * NHD];
    if (threadIdx.x < DE * NHD) wl[threadIdx.x] = WeAll[l * DE * NHD + threadIdx.x];
    __syncthreads();
    int tid = blockIdx.x * blockDim.x + threadIdx.x;
    if (tid >= E2 * NHD) return;
    int s = tid / NHD, hh = tid % NHD;
    int eid = eidx[s];
    const float* ar = (eid < NE) ? (ea + (size_t)eid * DE) : (loop + (size_t)(eid - NE) * DE);
    float sm = 0.f;
#pragma unroll
    for (int d = 0; d < DE; ++d) sm += ar[d] * wl[d * NHD + hh];
    aeAll[(size_t)l * E2 * NHD + tid] = sm;
}

// ---------------- per-(node,head): alpha (stored) + running max + 1/z ----------------
__global__ void k_mz(const float* __restrict__ S, const float* __restrict__ ae,
                     const int* __restrict__ rp, const int* __restrict__ scsr,
                     float* __restrict__ alpha, float2* __restrict__ mz2) {
    int tid = blockIdx.x * blockDim.x + threadIdx.x;
    if (tid >= NN * NHD) return;
    int n = tid / NHD, h = tid - (tid / NHD) * NHD;
    int r0 = rp[n], r1 = rp[n + 1];
    float sd = S[(size_t)n * 20 + 10 + h];
    float m = -1e30f, z = 0.f;
    for (int s = r0; s < r1; ++s) {
        int sn = scsr[s];
        float a = S[(size_t)sn * 20 + h] + sd + ae[(size_t)s * NHD + h];
        a = (a > 0.f) ? a : 0.2f * a;
        alpha[(size_t)s * NHD + h] = a;
        float mn = fmaxf(m, a);
        z = z * __expf(m - mn) + __expf(a - mn);
        m = mn;
    }
    mz2[tid] = make_float2(m, 1.f / z);
}

// ---------------- fused layer: single-pass agg (LDS G tile) + MFMA + epilogue + next-S ----------------
// 512 threads = 8 waves, 32 nodes/block; wave w owns nodes w*4..w*4+3.
constexpr int CE = 6;   // slots per chunk (60 lanes = 6 slots x 10 heads)
__global__ __launch_bounds__(512) void k_layer(
        const float* __restrict__ alpha, const float2* __restrict__ mz2,
        const float* __restrict__ hin, const int* __restrict__ rp,
        const int* __restrict__ scsr, const unsigned short* __restrict__ Bt,
        const float* __restrict__ Wcn, float* __restrict__ Sout, int do_s,
        const float* __restrict__ bias, const float* __restrict__ gam,
        const float* __restrict__ bet, const float* __restrict__ mean,
        const float* __restrict__ var, float* __restrict__ hout) {
    __shared__ __align__(16) unsigned short Gl[32][648];  // 41472 B
    __shared__ __align__(16) float pool[2112];            // 8448 B
    float* wch = pool;                    // [32][60] during Phase A
    int*   snl = (int*)(pool + 1920);     // [32][6]  during Phase A
    float* Wcl = pool;                    // [64*20]  after Phase A (alias)

    const int tid = threadIdx.x;
    const int w = tid >> 6, lane = tid & 63;
    const int el = lane / NHD, hh = lane - el * NHD;  // valid for lane<60
    const int blk = blockIdx.x;
    const int nb = blk * 32 + w * 4;

    // ---- stage first chunks of all 4 nodes (all loads in flight, no barriers) ----
    int r0a[4], dga[4];
    float wreg[4]; int sreg[4];
#pragma unroll
    for (int i = 0; i < 4; ++i) {
        const int n = nb + i;
        int r0 = 0, dg = 0;
        if (n < NN) { r0 = rp[n]; dg = rp[n + 1] - r0; }
        r0a[i] = r0; dga[i] = dg;
        float wv = 0.f;
        if (lane < CE * NHD && el < dg) {
            float a = alpha[(size_t)r0 * NHD + lane];       // contiguous 240B
            float2 mz = mz2[(size_t)n * NHD + hh];
            wv = __expf(a - mz.x) * mz.y;
        }
        wreg[i] = wv;
        if (lane < CE) sreg[i] = (lane < dg) ? scsr[r0 + lane] : ((n < NN) ? n : 0);
    }
#pragma unroll
    for (int i = 0; i < 4; ++i) {
        const int li = w * 4 + i;
        if (lane < CE * NHD) wch[li * 60 + lane] = wreg[i];
        if (lane < CE)       snl[li * CE + lane] = sreg[i];
    }
    __builtin_amdgcn_wave_barrier();

    // ---- accumulate per node (lane = feature) ----
    for (int i = 0; i < 4; ++i) {
        const int li = w * 4 + i;
        const int n = nb + i;
        float g[NHD];
#pragma unroll
        for (int q = 0; q < NHD; ++q) g[q] = 0.f;
        {
            int sv[CE]; float hv[CE];
#pragma unroll
            for (int j = 0; j < CE; ++j) sv[j] = snl[li * CE + j];
#pragma unroll
            for (int j = 0; j < CE; ++j) hv[j] = hin[(size_t)sv[j] * DH + lane];
#pragma unroll
            for (int j = 0; j < CE; ++j)
#pragma unroll
                for (int q = 0; q < NHD; ++q) g[q] += wch[li * 60 + j * NHD + q] * hv[j];
        }
        // tail chunks (deg > 6, ~8% of nodes)
        const int dg = dga[i];
        for (int c0 = CE; c0 < dg; c0 += CE) {
            __builtin_amdgcn_wave_barrier();
            if (lane < CE * NHD) {
                float wv = 0.f;
                if (el < dg - c0) {
                    float a = alpha[(size_t)(r0a[i] + c0) * NHD + lane];
                    float2 mz = mz2[(size_t)n * NHD + hh];
                    wv = __expf(a - mz.x) * mz.y;
                }
                wch[li * 60 + lane] = wv;
            }
            if (lane < CE) snl[li * CE + lane] = (c0 + lane < dg) ? scsr[r0a[i] + c0 + lane] : n;
            __builtin_amdgcn_wave_barrier();
            int sv[CE]; float hv[CE];
#pragma unroll
            for (int j = 0; j < CE; ++j) sv[j] = snl[li * CE + j];
#pragma unroll
            for (int j = 0; j < CE; ++j) hv[j] = hin[(size_t)sv[j] * DH + lane];
#pragma unroll
            for (int j = 0; j < CE; ++j)
#pragma unroll
                for (int q = 0; q < NHD; ++q) g[q] += wch[li * 60 + j * NHD + q] * hv[j];
        }
        // write G row (zeros for invalid nodes: wv were 0)
#pragma unroll
        for (int q = 0; q < NHD; ++q) Gl[li][q * 64 + lane] = f2bf(g[q]);
    }

    __syncthreads();

    // Wcl load (aliases wch pool — Phase A fully done) overlaps MFMA below
    if (do_s) for (int i = tid; i < DH * 20; i += 512) Wcl[i] = Wcn[i];

    // ---- Phase B: xc = G @ B, one 16x16 MFMA tile per wave ----
    const int rt = w & 1;             // row tile (16 nodes)
    const int ct = w >> 1;            // col tile (16 features)
    const int la = lane & 15, lb = lane >> 4;
    v4f acc = {0.f, 0.f, 0.f, 0.f};
    const size_t brow = (size_t)(ct * 16 + la) * 640;
#pragma unroll 5
    for (int t = 0; t < 20; ++t) {
        const int koff = t * 32 + lb * 8;
        v8s av = *(const v8s*)&Gl[rt * 16 + la][koff];
        v8s bv = *(const v8s*)&Bt[brow + koff];
        acc = __builtin_amdgcn_mfma_f32_16x16x32_bf16(
                  __builtin_bit_cast(v8bf, av), __builtin_bit_cast(v8bf, bv), acc, 0, 0, 0);
    }
    __syncthreads();                  // Gl reads done; allow alias writes below

    // epilogue: bias + BN + gelu + residual; stash hout tile in LDS (alias Gl, stride 65)
    float* hl = (float*)&Gl[0][0];    // [32][65] floats = 8.3 KB < 41.5 KB
    const int f = ct * 16 + la;
    const float bi = bias[f], gm = gam[f], bt_ = bet[f], mu = mean[f];
    const float iv = rsqrtf(var[f] + 1e-5f);
#pragma unroll
    for (int r = 0; r < 4; ++r) {
        const int local = rt * 16 + lb * 4 + r;
        const int n = blk * 32 + local;
        float hvold = (n < NN) ? hin[(size_t)n * DH + f] : 0.f;
        float v = acc[r] + bi;
        v = (v - mu) * gm * iv + bt_;
        v = 0.5f * v * (1.0f + erff(v * 0.70710678118654752f));
        float hnew = hvold + v;
        if (n < NN) hout[(size_t)n * DH + f] = hnew;
        hl[local * 65 + f] = hnew;
    }

    // fused next-layer scores: S[n][j] = hout[n] . Wcomb_next[:,j]
    if (do_s) {
        __syncthreads();
        for (int it = tid; it < 32 * 20; it += 512) {
            int local = it / 20, j = it % 20;
            int n = blk * 32 + local;
            if (n < NN) {
                const float* hr = &hl[local * 65];
                float s = 0.f;
#pragma unroll 16
                for (int k = 0; k < DH; ++k) s += hr[k] * Wcl[k * 20 + j];
                Sout[(size_t)n * 20 + j] = s;
            }
        }
    }
}

// ---------------- readout: out[g] = (segsum(h)[g] @ W_out + cnt*b_out) / max(cnt,1) ----------------
__global__ __launch_bounds__(256) void k_gout(const float* __restrict__ h,
        const float* __restrict__ W, const float* __restrict__ b,
        const int* __restrict__ grp, float* __restrict__ out) {
    __shared__ float Wl[DH * DOUTC];  // 32 KB
    __shared__ float hl[4][DH];
    __shared__ float cl[4];
    for (int i = threadIdx.x; i < DH * DOUTC; i += 256) Wl[i] = W[i];
    int w = threadIdx.x >> 6, lane = threadIdx.x & 63;
    int g = blockIdx.x * 4 + w;
    int r0 = grp[g], r1 = grp[g + 1];
    float s = 0.f;
    for (int n = r0; n < r1; ++n) s += h[(size_t)n * DH + lane];
    hl[w][lane] = s;
    if (lane == 0) cl[w] = (float)(r1 - r0);
    __syncthreads();
    for (int idx = threadIdx.x; idx < 4 * DOUTC; idx += 256) {
        int gi = idx >> 7, c = idx & 127;
        float cnt = cl[gi];
        float inv = 1.f / fmaxf(cnt, 1.f);
        float acc = cnt * b[c];
        const float* hr = hl[gi];
#pragma unroll 16
        for (int k = 0; k < DH; ++k) acc += hr[k] * Wl[k * DOUTC + c];
        out[(size_t)(blockIdx.x * 4 + gi) * DOUTC + c] = acc * inv;
    }
}

// ---------------- launcher ----------------
extern "C" void kernel_launch(void* const* d_in, const int* in_sizes, int n_in,
                              void* d_out, int out_size, void* d_ws, size_t ws_size,
                              hipStream_t stream) {
    const float* x        = (const float*)d_in[0];
    const float* edge_attr= (const float*)d_in[1];
    const float* W_emb    = (const float*)d_in[2];
    const float* b_emb    = (const float*)d_in[3];
    const float* Ws       = (const float*)d_in[4];
    const float* att_src  = (const float*)d_in[5];
    const float* att_dst  = (const float*)d_in[6];
    const float* att_edge = (const float*)d_in[7];
    const float* W_edge   = (const float*)d_in[8];
    const float* bias     = (const float*)d_in[9];
    const float* bn_gamma = (const float*)d_in[10];
    const float* bn_beta  = (const float*)d_in[11];
    const float* bn_mean  = (const float*)d_in[12];
    const float* bn_var   = (const float*)d_in[13];
    const float* W_out    = (const float*)d_in[14];
    const float* b_out    = (const float*)d_in[15];
    const int*   srcp     = (const int*)d_in[16];
    const int*   dstp     = srcp + NE;
    const int*   batch    = (const int*)d_in[17];
    float* out = (float*)d_out;

    char* wsb = (char*)d_ws;
    size_t off = 0;
    auto alloc = [&](size_t bytes) -> void* {
        void* p = (void*)(wsb + off);
        off += (bytes + 255) & ~(size_t)255;
        return p;
    };
    float* h0    = (float*)alloc((size_t)NN * DH * 4);
    float* h1    = (float*)alloc((size_t)NN * DH * 4);
    float* S     = (float*)alloc((size_t)NN * 20 * 4);
    float* aeAll = (float*)alloc((size_t)NL * E2 * NHD * 4);
    float* alpha = (float*)alloc((size_t)E2 * NHD * 4);
    float2* mz2  = (float2*)alloc((size_t)NN * NHD * 8);
    float* loop  = (float*)alloc((size_t)NN * DE * 4);
    int*   cnt   = (int*)alloc((size_t)NN * 4);
    int*   rp    = (int*)alloc((size_t)(NN + 1) * 4);
    int*   cursor= (int*)alloc((size_t)NN * 4);
    int*   eidx  = (int*)alloc((size_t)E2 * 4);
    int*   scsr  = (int*)alloc((size_t)E2 * 4);
    int*   bsum  = (int*)alloc((size_t)SCAN_NB * 4);
    int*   grp   = (int*)alloc((size_t)(NG + 1) * 4);
    float* WcombA= (float*)alloc((size_t)NL * DH * 20 * 4);
    float* WeA   = (float*)alloc((size_t)NL * DE * NHD * 4);
    unsigned short* BtA = (unsigned short*)alloc((size_t)NL * DH * 640 * 2);

    hipMemsetAsync(cnt,    0, (size_t)NN * 4, stream);
    hipMemsetAsync(cursor, 0, (size_t)NN * 4, stream);

    // preprocessing: CSR (eidx/scsr) + self-loop attrs + graph ptrs
    k_cnt<<<(NE + 255) / 256, 256, 0, stream>>>(dstp, cnt);
    k_scan_a<<<SCAN_NB, SCAN_B, 0, stream>>>(cnt, bsum);
    k_scan_b<<<1, 64, 0, stream>>>(bsum);
    k_scan_c<<<SCAN_NB, SCAN_B, 0, stream>>>(cnt, bsum, rp);
    k_csr_fill<<<(E2 + 255) / 256, 256, 0, stream>>>(srcp, dstp, rp, cursor, eidx, scsr);
    k_loopattr<<<(NN * DE + 255) / 256, 256, 0, stream>>>(rp, eidx, cnt, edge_attr, loop);
    k_grp<<<(NN + 255) / 256, 256, 0, stream>>>(batch, grp);

    // per-layer constants
    {
        dim3 g(6, NL);
        k_comb3<<<g, 256, 0, stream>>>(Ws, att_src, att_dst, W_edge, att_edge, WcombA, WeA);
    }
    {
        dim3 g((DH * 640 + 255) / 256, NL);
        k_prepB3<<<g, 256, 0, stream>>>(Ws, BtA);
    }
    {
        dim3 g((E2 * NHD + 255) / 256, NL);
        k_aecsr<<<g, 256, 0, stream>>>(edge_attr, loop, WeA, eidx, aeAll);
    }

    // embedding + fused layer-0 scores
    k_emb<<<(NN + 3) / 4, 256, 0, stream>>>(x, W_emb, b_emb, WcombA, h0, S);

    float* hb[2] = {h0, h1};
    for (int l = 0; l < NL; ++l) {
        float* hin  = hb[l & 1];
        float* hout = hb[(l + 1) & 1];
        k_mz<<<(NN * NHD + 255) / 256, 256, 0, stream>>>(
            S, aeAll + (size_t)l * E2 * NHD, rp, scsr, alpha, mz2);
        k_layer<<<(NN + 31) / 32, 512, 0, stream>>>(
            alpha, mz2, hin, rp, scsr, BtA + (size_t)l * DH * 640,
            WcombA + (size_t)(l + 1 < NL ? l + 1 : 0) * DH * 20, S, (l + 1 < NL) ? 1 : 0,
            bias + l * DH, bn_gamma + l * DH, bn_beta + l * DH,
            bn_mean + l * DH, bn_var + l * DH, hout);
    }
    float* hfin = hb[NL & 1];

    // readout
    k_gout<<<NG / 4, 256, 0, stream>>>(hfin, W_out, b_out, grp, out);
}

// Round 6
// 327.598 us; speedup vs baseline: 2.4209x; 1.1493x over previous
//
#include <hip/hip_runtime.h>
#include <math.h>

// ---------------- problem constants ----------------
constexpr int NN   = 50000;          // nodes
constexpr int NE   = 150000;         // edges
constexpr int DIN  = 48;
constexpr int DH   = 64;
constexpr int DE   = 16;
constexpr int NHD  = 10;             // heads
constexpr int NL   = 3;              // layers
constexpr int DOUTC= 128;
constexpr int NG   = 4096;           // graphs
constexpr int E2   = NE + NN;        // edges incl self loops
constexpr int SCAN_B  = 256;
constexpr int SCAN_NB = (NN + SCAN_B - 1) / SCAN_B;   // 196

typedef __bf16 v8bf __attribute__((ext_vector_type(8)));
typedef short  v8s  __attribute__((ext_vector_type(8)));
typedef float  v4f  __attribute__((ext_vector_type(4)));

__device__ inline unsigned short f2bf(float f) {
    unsigned u = __builtin_bit_cast(unsigned, f);
    unsigned r = (u + 0x7FFFu + ((u >> 16) & 1u)) >> 16;
    return (unsigned short)r;
}

// broadcast a float/int from a compile-time lane (no LDS)
#define RLF(v, l) __builtin_bit_cast(float, __builtin_amdgcn_readlane(__builtin_bit_cast(int, (v)), (l)))
#define RLI(v, l) __builtin_amdgcn_readlane((v), (l))

// ---------------- preprocessing ----------------
__global__ void k_cnt(const int* __restrict__ dst, int* __restrict__ cnt) {
    int e = blockIdx.x * blockDim.x + threadIdx.x;
    if (e < NE) atomicAdd(&cnt[dst[e]], 1);
}

__global__ void k_scan_a(const int* __restrict__ cnt, int* __restrict__ bsum) {
    __shared__ int s[SCAN_B];
    int i = blockIdx.x * SCAN_B + threadIdx.x;
    s[threadIdx.x] = (i < NN) ? (cnt[i] + 1) : 0;   // +1 = self loop
    __syncthreads();
    for (int off = SCAN_B / 2; off > 0; off >>= 1) {
        if (threadIdx.x < off) s[threadIdx.x] += s[threadIdx.x + off];
        __syncthreads();
    }
    if (threadIdx.x == 0) bsum[blockIdx.x] = s[0];
}

__global__ void k_scan_b(int* __restrict__ bsum) {
    if (threadIdx.x == 0 && blockIdx.x == 0) {
        int acc = 0;
        for (int i = 0; i < SCAN_NB; ++i) { int v = bsum[i]; bsum[i] = acc; acc += v; }
    }
}

__global__ void k_scan_c(const int* __restrict__ cnt, const int* __restrict__ bsum,
                         int* __restrict__ rp) {
    __shared__ int s[SCAN_B];
    int i = blockIdx.x * SCAN_B + threadIdx.x;
    int v = (i < NN) ? (cnt[i] + 1) : 0;
    s[threadIdx.x] = v;
    __syncthreads();
    for (int off = 1; off < SCAN_B; off <<= 1) {
        int t = (threadIdx.x >= off) ? s[threadIdx.x - off] : 0;
        __syncthreads();
        s[threadIdx.x] += t;
        __syncthreads();
    }
    if (i < NN) {
        int excl = bsum[blockIdx.x] + s[threadIdx.x] - v;
        rp[i] = excl;
        if (i == NN - 1) rp[NN] = excl + v;
    }
}

__global__ void k_csr_fill(const int* __restrict__ src, const int* __restrict__ dst,
                           const int* __restrict__ rp, int* __restrict__ cursor,
                           int* __restrict__ eidx, int* __restrict__ scsr) {
    int e = blockIdx.x * blockDim.x + threadIdx.x;
    if (e >= E2) return;
    int d  = (e < NE) ? dst[e] : (e - NE);
    int sn = (e < NE) ? src[e] : d;
    int pos = atomicAdd(&cursor[d], 1);
    int s = rp[d] + pos;
    eidx[s] = e; scsr[s] = sn;
}

// self-loop attr = mean of real incoming edge attrs (no atomics, via CSR)
__global__ void k_loopattr(const int* __restrict__ rp, const int* __restrict__ eidx,
                           const int* __restrict__ cnt, const float* __restrict__ ea,
                           float* __restrict__ loop) {
    int tid = blockIdx.x * blockDim.x + threadIdx.x;
    if (tid >= NN * DE) return;
    int n = tid >> 4, d = tid & 15;
    int r0 = rp[n], r1 = rp[n + 1];
    float s = 0.f;
    for (int t = r0; t < r1; ++t) {
        int eid = eidx[t];
        if (eid < NE) s += ea[(size_t)eid * DE + d];
    }
    int c = cnt[n];
    loop[tid] = s * ((c > 1) ? (1.0f / (float)c) : 1.0f);
}

// graph row pointers from sorted batch ids
__global__ void k_grp(const int* __restrict__ batch, int* __restrict__ grp) {
    int n = blockIdx.x * blockDim.x + threadIdx.x;
    if (n >= NN) return;
    int b = batch[n];
    int pb = (n == 0) ? -1 : batch[n - 1];
    for (int g = pb + 1; g <= b; ++g) grp[g] = n;
    if (n == NN - 1) for (int g = b + 1; g <= NG; ++g) grp[g] = NN;
}

// ---------------- embedding GEMM + fused layer-0 scores ----------------
__global__ __launch_bounds__(256) void k_emb(const float* __restrict__ x,
        const float* __restrict__ W, const float* __restrict__ b,
        const float* __restrict__ Wc, float* __restrict__ h, float* __restrict__ S) {
    __shared__ float Wl[DIN * DH];      // 12 KB
    __shared__ float Wcl[DH * 20];      // 5 KB
    __shared__ float hl[4][DH];         // 1 KB
    for (int i = threadIdx.x; i < DIN * DH; i += 256) Wl[i] = W[i];
    for (int i = threadIdx.x; i < DH * 20; i += 256) Wcl[i] = Wc[i];
    __syncthreads();
    int w = threadIdx.x >> 6, c = threadIdx.x & 63;
    int n = blockIdx.x * 4 + w;
    float acc = b[c];
    if (n < NN) {
        const float* xr = x + (size_t)n * DIN;
#pragma unroll
        for (int k = 0; k < DIN; ++k) acc += xr[k] * Wl[k * DH + c];
        h[(size_t)n * DH + c] = acc;
    }
    hl[w][c] = acc;
    __syncthreads();
    if (threadIdx.x < 4 * 20) {
        int wi = threadIdx.x / 20, j = threadIdx.x % 20;
        int nn = blockIdx.x * 4 + wi;
        if (nn < NN) {
            const float* hr = hl[wi];
            float s = 0.f;
#pragma unroll 16
            for (int k = 0; k < DH; ++k) s += hr[k] * Wcl[k * 20 + j];
            S[(size_t)nn * 20 + j] = s;
        }
    }
}

// ---------------- all-layer combined attention weights ----------------
__global__ void k_comb3(const float* __restrict__ Ws, const float* __restrict__ asrc,
                        const float* __restrict__ adst, const float* __restrict__ We_in,
                        const float* __restrict__ aedge, float* __restrict__ Wcomb,
                        float* __restrict__ We) {
    int layer = blockIdx.y;
    int tid = blockIdx.x * blockDim.x + threadIdx.x;
    if (tid < DH * 2 * NHD) {                      // 1280
        int k = tid / 20, j = tid % 20;
        int hh = j % NHD;
        const float* a = ((j < NHD) ? asrc : adst) + (size_t)layer * NHD * DH + hh * DH;
        const float* w = Ws + ((size_t)layer * DH + k) * (NHD * DH) + hh * DH;
        float s = 0.f;
#pragma unroll
        for (int f = 0; f < DH; ++f) s += w[f] * a[f];
        Wcomb[layer * 1280 + tid] = s;
    } else if (tid < DH * 2 * NHD + DE * NHD) {    // +160
        int t = tid - DH * 2 * NHD;
        int d = t / NHD, hh = t % NHD;
        const float* a = aedge + (size_t)layer * NHD * DH + hh * DH;
        const float* w = We_in + ((size_t)layer * DE + d) * (NHD * DH) + hh * DH;
        float s = 0.f;
#pragma unroll
        for (int f = 0; f < DH; ++f) s += w[f] * a[f];
        We[layer * 160 + t] = s;
    }
}

// ---------------- Bt[l][f][j'] with j' = k*10+q : B[j'][f] = Ws[l][k][q*64+f]*0.1, bf16 ----------------
__global__ void k_prepB3(const float* __restrict__ Ws, unsigned short* __restrict__ Bt) {
    int layer = blockIdx.y;
    int tid = blockIdx.x * blockDim.x + threadIdx.x;
    if (tid >= DH * 640) return;
    int f = tid / 640, jp = tid % 640;
    int k = jp / 10, q = jp % 10;
    float v = Ws[(size_t)layer * DH * 640 + (size_t)k * 640 + q * 64 + f] * 0.1f;
    Bt[(size_t)layer * DH * 640 + tid] = f2bf(v);
}

// ---------------- Wcomb in MFMA B-fragment layout (bf16), per layer, 2 col-tiles ----------------
__global__ void k_wcb(const float* __restrict__ Wcomb, unsigned short* __restrict__ WcB) {
    int tid = blockIdx.x * blockDim.x + threadIdx.x;
    if (tid >= NL * 2 * 64 * 16) return;
    int l = tid / 2048, r = tid % 2048;
    int tile = r / 1024, rr = r % 1024;
    int ln = rr / 16, idx = rr % 16;
    int t = idx / 8, e = idx % 8;
    int k = t * 32 + (ln >> 4) * 8 + e;
    int jc = ln & 15;
    float v = 0.f;
    if (tile == 0 || jc < 4) v = Wcomb[l * 1280 + k * 20 + tile * 16 + jc];
    WcB[tid] = f2bf(v);
}

// ---------------- a_e in CSR slot order, all 3 layers ----------------
__global__ void k_aecsr(const float* __restrict__ ea, const float* __restrict__ loop,
                        const float* __restrict__ WeAll, const int* __restrict__ eidx,
                        float* __restrict__ aeAll) {
    int l = blockIdx.y;
    __shared__ float wl[DE * NHD];
    if (threadIdx.x < DE * NHD) wl[threadIdx.x] = WeAll[l * DE * NHD + threadIdx.x];
    __syncthreads();
    int tid = blockIdx.x * blockDim.x + threadIdx.x;
    if (tid >= E2 * NHD) return;
    int s = tid / NHD, hh = tid % NHD;
    int eid = eidx[s];
    const float* ar = (eid < NE) ? (ea + (size_t)eid * DE) : (loop + (size_t)(eid - NE) * DE);
    float sm = 0.f;
#pragma unroll
    for (int d = 0; d < DE; ++d) sm += ar[d] * wl[d * NHD + hh];
    aeAll[(size_t)l * E2 * NHD + tid] = sm;
}

// ---------------- per-(node,head): alpha -> softmax weights w (in place, 2 passes) ----------------
__global__ void k_mz(const float* __restrict__ S, const float* __restrict__ ae,
                     const int* __restrict__ rp, const int* __restrict__ scsr,
                     float* __restrict__ wout) {
    int tid = blockIdx.x * blockDim.x + threadIdx.x;
    if (tid >= NN * NHD) return;
    int n = tid / NHD, h = tid - (tid / NHD) * NHD;
    int r0 = rp[n], r1 = rp[n + 1];
    float sd = S[(size_t)n * 20 + 10 + h];
    float m = -1e30f, z = 0.f;
    for (int s = r0; s < r1; ++s) {
        int sn = scsr[s];
        float a = S[(size_t)sn * 20 + h] + sd + ae[(size_t)s * NHD + h];
        a = (a > 0.f) ? a : 0.2f * a;
        wout[(size_t)s * NHD + h] = a;
        float mn = fmaxf(m, a);
        z = z * __expf(m - mn) + __expf(a - mn);
        m = mn;
    }
    float zi = 1.f / z;
    for (int s = r0; s < r1; ++s) {
        float a = wout[(size_t)s * NHD + h];
        wout[(size_t)s * NHD + h] = __expf(a - m) * zi;
    }
}

// ---------------- fused layer: reg-only agg -> LDS G tile -> MFMA -> epilogue -> next-S MFMA ----------------
// 256 threads = 4 waves, 16 nodes/block (grid exact: 3125*16 = 50000); wave w owns nodes w*4..w*4+3.
__global__ __launch_bounds__(256) void k_layer(
        const float* __restrict__ wbuf, const float* __restrict__ hin,
        const int* __restrict__ rp, const int* __restrict__ scsr,
        const unsigned short* __restrict__ Bt, const unsigned short* __restrict__ WcB,
        int do_s, float* __restrict__ Sout,
        const float* __restrict__ bias, const float* __restrict__ gam,
        const float* __restrict__ bet, const float* __restrict__ mean,
        const float* __restrict__ var, float* __restrict__ hout) {
    __shared__ __align__(16) unsigned short Gl[16 * 648];   // 20736 B (row stride 648 bf16)

    const int tid = threadIdx.x;
    const int w = tid >> 6, lane = tid & 63;
    const int el = lane / NHD;          // slot within chunk for staging lanes (<60)
    const int blk = blockIdx.x;
    const int nb4 = blk * 16 + w * 4;

    // ---- Phase A: stage w + src for 4 nodes, all loads in flight ----
    int r0a[4], dga[4]; float wreg[4]; int sreg[4];
#pragma unroll
    for (int i = 0; i < 4; ++i) {
        int n = nb4 + i;
        int r0 = rp[n], dg = rp[n + 1] - r0;
        r0a[i] = r0; dga[i] = dg;
        wreg[i] = (lane < 60 && el < dg) ? wbuf[(size_t)r0 * NHD + lane] : 0.f;
        sreg[i] = (lane < 6) ? ((lane < dg) ? scsr[r0 + lane] : n) : 0;
    }
    float hv[4][6];
#pragma unroll
    for (int i = 0; i < 4; ++i) {
#pragma unroll
        for (int j = 0; j < 6; ++j) {
            int sv = RLI(sreg[i], j);
            hv[i][j] = hin[(size_t)sv * DH + lane];
        }
    }
#pragma unroll
    for (int i = 0; i < 4; ++i) {
        float g[NHD];
#pragma unroll
        for (int q = 0; q < NHD; ++q) g[q] = 0.f;
#pragma unroll
        for (int j = 0; j < 6; ++j) {
#pragma unroll
            for (int q = 0; q < NHD; ++q)
                g[q] = fmaf(RLF(wreg[i], j * 10 + q), hv[i][j], g[q]);
        }
        // tail chunks (deg > 6)
        for (int c0 = 6; c0 < dga[i]; c0 += 6) {
            float w2 = (lane < 60 && el < dga[i] - c0) ? wbuf[(size_t)(r0a[i] + c0) * NHD + lane] : 0.f;
            int s2 = (lane < 6 && c0 + lane < dga[i]) ? scsr[r0a[i] + c0 + lane] : (nb4 + i);
            float hv2[6];
#pragma unroll
            for (int j = 0; j < 6; ++j) {
                int sv = RLI(s2, j);
                hv2[j] = hin[(size_t)sv * DH + lane];
            }
#pragma unroll
            for (int j = 0; j < 6; ++j)
#pragma unroll
                for (int q = 0; q < NHD; ++q)
                    g[q] = fmaf(RLF(w2, j * 10 + q), hv2[j], g[q]);
        }
        // write G row: G[li][k*10+q], lane=k holds 10 consecutive bf16 -> 5 packed b32
        const int li = w * 4 + i;
        const int base = li * 648 + lane * 10;
#pragma unroll
        for (int p = 0; p < 5; ++p) {
            unsigned u = (unsigned)f2bf(g[2 * p]) | ((unsigned)f2bf(g[2 * p + 1]) << 16);
            *(unsigned*)&Gl[base + 2 * p] = u;
        }
    }
    __syncthreads();

    // ---- Phase B: xc = G @ B, one 16x16 MFMA col-tile per wave (K = 640) ----
    const int la = lane & 15, lb = lane >> 4;
    v4f acc = {0.f, 0.f, 0.f, 0.f};
    const size_t brow = (size_t)(w * 16 + la) * 640;
#pragma unroll 5
    for (int t = 0; t < 20; ++t) {
        const int koff = t * 32 + lb * 8;
        v8s av = *(const v8s*)&Gl[la * 648 + koff];
        v8s bv = *(const v8s*)&Bt[brow + koff];
        acc = __builtin_amdgcn_mfma_f32_16x16x32_bf16(
                  __builtin_bit_cast(v8bf, av), __builtin_bit_cast(v8bf, bv), acc, 0, 0, 0);
    }
    __syncthreads();      // all Gl reads done; epilogue reuses Gl as bf16 h-tile

    // ---- epilogue: bias + BN + gelu + residual; stash hout tile (bf16) in LDS ----
    unsigned short* hlb = Gl;           // [16][72] bf16 = 2304 B (alias)
    const int f = w * 16 + la;
    const float bi = bias[f], gm = gam[f], bt_ = bet[f], mu = mean[f];
    const float iv = rsqrtf(var[f] + 1e-5f);
#pragma unroll
    for (int r = 0; r < 4; ++r) {
        const int local = lb * 4 + r;
        const int n = blk * 16 + local;
        float hvold = hin[(size_t)n * DH + f];
        float v = acc[r] + bi;
        v = (v - mu) * gm * iv + bt_;
        v = 0.5f * v * (1.0f + erff(v * 0.70710678118654752f));
        float hnew = hvold + v;
        hout[(size_t)n * DH + f] = hnew;
        hlb[local * 72 + f] = f2bf(hnew);
    }

    // ---- fused next-layer scores: S[16 nodes][20] = h_tile @ Wc via 1 MFMA per col-tile ----
    if (do_s) {
        __syncthreads();
        if (w < 2) {
            v4f sa = {0.f, 0.f, 0.f, 0.f};
#pragma unroll
            for (int t = 0; t < 2; ++t) {
                v8s av = *(const v8s*)&hlb[la * 72 + t * 32 + lb * 8];
                v8s bv = *(const v8s*)&WcB[(size_t)(w * 64 + lane) * 16 + t * 8];
                sa = __builtin_amdgcn_mfma_f32_16x16x32_bf16(
                         __builtin_bit_cast(v8bf, av), __builtin_bit_cast(v8bf, bv), sa, 0, 0, 0);
            }
            if (w == 0) {
#pragma unroll
                for (int r = 0; r < 4; ++r) {
                    int n = blk * 16 + lb * 4 + r;
                    Sout[(size_t)n * 20 + la] = sa[r];
                }
            } else if (la < 4) {
#pragma unroll
                for (int r = 0; r < 4; ++r) {
                    int n = blk * 16 + lb * 4 + r;
                    Sout[(size_t)n * 20 + 16 + la] = sa[r];
                }
            }
        }
    }
}

// ---------------- readout: out[g] = (segsum(h)[g] @ W_out + cnt*b_out) / max(cnt,1) ----------------
__global__ __launch_bounds__(256) void k_gout(const float* __restrict__ h,
        const float* __restrict__ W, const float* __restrict__ b,
        const int* __restrict__ grp, float* __restrict__ out) {
    __shared__ float Wl[DH * DOUTC];  // 32 KB
    __shared__ float hl[4][DH];
    __shared__ float cl[4];
    for (int i = threadIdx.x; i < DH * DOUTC; i += 256) Wl[i] = W[i];
    int w = threadIdx.x >> 6, lane = threadIdx.x & 63;
    int g = blockIdx.x * 4 + w;
    int r0 = grp[g], r1 = grp[g + 1];
    float s = 0.f;
    for (int n = r0; n < r1; ++n) s += h[(size_t)n * DH + lane];
    hl[w][lane] = s;
    if (lane == 0) cl[w] = (float)(r1 - r0);
    __syncthreads();
    for (int idx = threadIdx.x; idx < 4 * DOUTC; idx += 256) {
        int gi = idx >> 7, c = idx & 127;
        float cnt = cl[gi];
        float inv = 1.f / fmaxf(cnt, 1.f);
        float acc = cnt * b[c];
        const float* hr = hl[gi];
#pragma unroll 16
        for (int k = 0; k < DH; ++k) acc += hr[k] * Wl[k * DOUTC + c];
        out[(size_t)(blockIdx.x * 4 + gi) * DOUTC + c] = acc * inv;
    }
}

// ---------------- launcher ----------------
extern "C" void kernel_launch(void* const* d_in, const int* in_sizes, int n_in,
                              void* d_out, int out_size, void* d_ws, size_t ws_size,
                              hipStream_t stream) {
    const float* x        = (const float*)d_in[0];
    const float* edge_attr= (const float*)d_in[1];
    const float* W_emb    = (const float*)d_in[2];
    const float* b_emb    = (const float*)d_in[3];
    const float* Ws       = (const float*)d_in[4];
    const float* att_src  = (const float*)d_in[5];
    const float* att_dst  = (const float*)d_in[6];
    const float* att_edge = (const float*)d_in[7];
    const float* W_edge   = (const float*)d_in[8];
    const float* bias     = (const float*)d_in[9];
    const float* bn_gamma = (const float*)d_in[10];
    const float* bn_beta  = (const float*)d_in[11];
    const float* bn_mean  = (const float*)d_in[12];
    const float* bn_var   = (const float*)d_in[13];
    const float* W_out    = (const float*)d_in[14];
    const float* b_out    = (const float*)d_in[15];
    const int*   srcp     = (const int*)d_in[16];
    const int*   dstp     = srcp + NE;
    const int*   batch    = (const int*)d_in[17];
    float* out = (float*)d_out;

    char* wsb = (char*)d_ws;
    size_t off = 0;
    auto alloc = [&](size_t bytes) -> void* {
        void* p = (void*)(wsb + off);
        off += (bytes + 255) & ~(size_t)255;
        return p;
    };
    float* h0    = (float*)alloc((size_t)NN * DH * 4);
    float* h1    = (float*)alloc((size_t)NN * DH * 4);
    float* S     = (float*)alloc((size_t)NN * 20 * 4);
    float* aeAll = (float*)alloc((size_t)NL * E2 * NHD * 4);
    float* wbuf  = (float*)alloc((size_t)E2 * NHD * 4);
    float* loop  = (float*)alloc((size_t)NN * DE * 4);
    int*   cnt   = (int*)alloc((size_t)NN * 4);
    int*   rp    = (int*)alloc((size_t)(NN + 1) * 4);
    int*   cursor= (int*)alloc((size_t)NN * 4);
    int*   eidx  = (int*)alloc((size_t)E2 * 4);
    int*   scsr  = (int*)alloc((size_t)E2 * 4);
    int*   bsum  = (int*)alloc((size_t)SCAN_NB * 4);
    int*   grp   = (int*)alloc((size_t)(NG + 1) * 4);
    float* WcombA= (float*)alloc((size_t)NL * DH * 20 * 4);
    float* WeA   = (float*)alloc((size_t)NL * DE * NHD * 4);
    unsigned short* BtA  = (unsigned short*)alloc((size_t)NL * DH * 640 * 2);
    unsigned short* WcB  = (unsigned short*)alloc((size_t)NL * 2 * 64 * 16 * 2);

    hipMemsetAsync(cnt,    0, (size_t)NN * 4, stream);
    hipMemsetAsync(cursor, 0, (size_t)NN * 4, stream);

    // preprocessing: CSR (eidx/scsr) + self-loop attrs + graph ptrs
    k_cnt<<<(NE + 255) / 256, 256, 0, stream>>>(dstp, cnt);
    k_scan_a<<<SCAN_NB, SCAN_B, 0, stream>>>(cnt, bsum);
    k_scan_b<<<1, 64, 0, stream>>>(bsum);
    k_scan_c<<<SCAN_NB, SCAN_B, 0, stream>>>(cnt, bsum, rp);
    k_csr_fill<<<(E2 + 255) / 256, 256, 0, stream>>>(srcp, dstp, rp, cursor, eidx, scsr);
    k_loopattr<<<(NN * DE + 255) / 256, 256, 0, stream>>>(rp, eidx, cnt, edge_attr, loop);
    k_grp<<<(NN + 255) / 256, 256, 0, stream>>>(batch, grp);

    // per-layer constants
    {
        dim3 g(6, NL);
        k_comb3<<<g, 256, 0, stream>>>(Ws, att_src, att_dst, W_edge, att_edge, WcombA, WeA);
    }
    {
        dim3 g((DH * 640 + 255) / 256, NL);
        k_prepB3<<<g, 256, 0, stream>>>(Ws, BtA);
    }
    k_wcb<<<(NL * 2 * 64 * 16 + 255) / 256, 256, 0, stream>>>(WcombA, WcB);
    {
        dim3 g((E2 * NHD + 255) / 256, NL);
        k_aecsr<<<g, 256, 0, stream>>>(edge_attr, loop, WeA, eidx, aeAll);
    }

    // embedding + fused layer-0 scores
    k_emb<<<(NN + 3) / 4, 256, 0, stream>>>(x, W_emb, b_emb, WcombA, h0, S);

    float* hb[2] = {h0, h1};
    for (int l = 0; l < NL; ++l) {
        float* hin  = hb[l & 1];
        float* hout = hb[(l + 1) & 1];
        k_mz<<<(NN * NHD + 255) / 256, 256, 0, stream>>>(
            S, aeAll + (size_t)l * E2 * NHD, rp, scsr, wbuf);
        k_layer<<<NN / 16, 256, 0, stream>>>(
            wbuf, hin, rp, scsr, BtA + (size_t)l * DH * 640,
            WcB + (size_t)(l + 1 < NL ? l + 1 : 0) * 2048,
            (l + 1 < NL) ? 1 : 0, S,
            bias + l * DH, bn_gamma + l * DH, bn_beta + l * DH,
            bn_mean + l * DH, bn_var + l * DH, hout);
    }
    float* hfin = hb[NL & 1];

    // readout
    k_gout<<<NG / 4, 256, 0, stream>>>(hfin, W_out, b_out, grp, out);
}